// Round 10
// baseline (822.104 us; speedup 1.0000x reference)
//
#include <hip/hip_runtime.h>

// ---------------------------------------------------------------------------
// GCN with edge sampling. FEATURE-SLICED layout: all intermediates stored as
// [slice][N][16] (slice = 16 feats = 64B f32 / 32B bf16). Aggregation blocks
// pick slice = blockIdx&7 -> XCD round-robin puts each slice's 1.6-3.2MB
// region on one XCD's L2 -> gathers are L2 hits instead of HBM misses.
//  Pass 1 (-> tz -> mask): split-bf16 MFMA GEMMs (3-plane, 6 terms, ~2^-26)
//  + f32 aggs (bit-identical products; order-only changes) -> mask stable.
//  Pass 2 (post-mask): bf16 end-to-end.
//  CSR build: bucket-radix, LDS atomics only.
// conv: out[v] = dinv[v]*(sum_e h[src]*dinv[src]*m[e] + h[v]*dinv[v]) + b
// ---------------------------------------------------------------------------

typedef __attribute__((ext_vector_type(8))) short bf16x8;
typedef __attribute__((ext_vector_type(4))) float f32x4;

__device__ inline unsigned bfpair(float lo, float hi) {   // pack 2 f32 -> bf16x2 RNE
    unsigned a = __float_as_uint(lo), b = __float_as_uint(hi);
    a = (a + 0x7FFFu + ((a >> 16) & 1u)) >> 16;
    b = (b + 0x7FFFu + ((b >> 16) & 1u)) & 0xFFFF0000u;
    return a | b;
}
__device__ inline unsigned short bf1(float v) {
    unsigned u = __float_as_uint(v);
    return (unsigned short)((u + 0x7FFFu + ((u >> 16) & 1u)) >> 16);
}
__device__ inline void unpack2(unsigned u, float& f0, float& f1) {
    f0 = __uint_as_float(u << 16);
    f1 = __uint_as_float(u & 0xFFFF0000u);
}

// ---------------- scans ----------------
__global__ void k_scan1(const int* __restrict__ in, int* __restrict__ out,
                        int* __restrict__ bsums, int N) {
    __shared__ int tmp[256];
    int i = blockIdx.x * 256 + threadIdx.x;
    int v = (i < N) ? in[i] : 0;
    tmp[threadIdx.x] = v;
    __syncthreads();
    for (int off = 1; off < 256; off <<= 1) {
        int t = (threadIdx.x >= off) ? tmp[threadIdx.x - off] : 0;
        __syncthreads();
        tmp[threadIdx.x] += t;
        __syncthreads();
    }
    if (i < N) out[i] = tmp[threadIdx.x] - v;
    if (threadIdx.x == 255) bsums[blockIdx.x] = tmp[255];
}

__global__ void k_scan2(int* __restrict__ bsums, int nb) {
    __shared__ int tmp[256];
    int v = (threadIdx.x < nb) ? bsums[threadIdx.x] : 0;
    tmp[threadIdx.x] = v;
    __syncthreads();
    for (int off = 1; off < 256; off <<= 1) {
        int t = (threadIdx.x >= off) ? tmp[threadIdx.x - off] : 0;
        __syncthreads();
        tmp[threadIdx.x] += t;
        __syncthreads();
    }
    if (threadIdx.x < nb) bsums[threadIdx.x] = tmp[threadIdx.x] - v;
}

__global__ void k_scan3(int* __restrict__ out, const int* __restrict__ bsums, int N, int E) {
    int i = blockIdx.x * 256 + threadIdx.x;
    if (i < N) out[i] += bsums[blockIdx.x];
    if (i == 0) out[N] = E;
}

// ---------------- bucket-radix CSR build ----------------
__global__ __launch_bounds__(256) void k_bcount(const int* __restrict__ dst,
                                                int* __restrict__ cnt, int E, int chunk) {
    __shared__ int h[1024];
    for (int i = threadIdx.x; i < 1024; i += 256) h[i] = 0;
    __syncthreads();
    int beg = blockIdx.x * chunk, end = min(E, beg + chunk);
    for (int e = beg + threadIdx.x; e < end; e += 256)
        atomicAdd(&h[dst[e] >> 6], 1);
    __syncthreads();
    for (int b = threadIdx.x; b < 1024; b += 256)
        cnt[b * 64 + blockIdx.x] = h[b];
}

__global__ __launch_bounds__(256) void k_bscatter(const int* __restrict__ src,
                                                  const int* __restrict__ dst,
                                                  const float* __restrict__ er,
                                                  const int* __restrict__ sbase,
                                                  int2* __restrict__ stg, int E, int chunk) {
    __shared__ int cur[1024];
    for (int i = threadIdx.x; i < 1024; i += 256) cur[i] = 0;
    __syncthreads();
    int beg = blockIdx.x * chunk, end = min(E, beg + chunk);
    for (int e = beg + threadIdx.x; e < end; e += 256) {
        int d = dst[e];
        int b = d >> 6;
        int loc = atomicAdd(&cur[b], 1);
        int pos = sbase[b * 64 + blockIdx.x] + loc;
        stg[pos] = make_int2(src[e] | ((d & 63) << 16), (int)__float_as_uint(er[e]));
    }
}

__global__ __launch_bounds__(256) void k_bindeg(const int2* __restrict__ stg,
                                                const int* __restrict__ sbase,
                                                int* __restrict__ indeg,
                                                float* __restrict__ dinvF, int N) {
    __shared__ int cnt[64];
    if (threadIdx.x < 64) cnt[threadIdx.x] = 0;
    __syncthreads();
    int b = blockIdx.x;
    int beg = sbase[b * 64], end = sbase[(b + 1) * 64];
    for (int i = beg + threadIdx.x; i < end; i += 256)
        atomicAdd(&cnt[(stg[i].x >> 16) & 63], 1);
    __syncthreads();
    if (threadIdx.x < 64) {
        int node = b * 64 + threadIdx.x;
        if (node < N) {
            int c = cnt[threadIdx.x];
            indeg[node] = c;
            dinvF[node] = 1.0f / sqrtf((float)c + 1.0f);
        }
    }
}

__global__ __launch_bounds__(256) void k_bfill(const int2* __restrict__ stg,
                                               const int* __restrict__ sbase,
                                               const int* __restrict__ csr_off,
                                               int2* __restrict__ csr_se, int N) {
    __shared__ int cur[64];
    int b = blockIdx.x;
    if (threadIdx.x < 64) {
        int node = b * 64 + threadIdx.x;
        cur[threadIdx.x] = (node < N) ? csr_off[node] : 0;
    }
    __syncthreads();
    int beg = sbase[b * 64], end = sbase[(b + 1) * 64];
    for (int i = beg + threadIdx.x; i < end; i += 256) {
        int2 se = stg[i];
        int j = (se.x >> 16) & 63;
        int pos = atomicAdd(&cur[j], 1);
        csr_se[pos] = make_int2(se.x & 0xFFFF, se.y);
    }
}

// mask in CSR order: block per node; also writes dinvM.
__global__ __launch_bounds__(128) void k_surv(const float* __restrict__ tz,
                                              const int* __restrict__ csr_off,
                                              const int2* __restrict__ csr_se,
                                              float* __restrict__ survive,
                                              float* __restrict__ dinvM, int N) {
    const int v = blockIdx.x;
    const int l = threadIdx.x & 15;
    const int s = threadIdx.x >> 4;
    const int e0 = csr_off[v];
    const int e1 = csr_off[v + 1];
    const float4 tv = *(const float4*)&tz[(size_t)v * 64 + l * 4];
    int cnt = 0;
    for (int i = e0 + s; i < e1; i += 8) {
        int2 se = csr_se[i];
        const float4 a = *(const float4*)&tz[(size_t)se.x * 64 + l * 4];
        float p = a.x * tv.x + a.y * tv.y + a.z * tv.z + a.w * tv.w;
        p += __shfl_xor(p, 1, 16);
        p += __shfl_xor(p, 2, 16);
        p += __shfl_xor(p, 4, 16);
        p += __shfl_xor(p, 8, 16);
        float sg = 1.0f / (1.0f + expf(-p));
        float m = (sg > __uint_as_float((unsigned)se.y)) ? 1.0f : 0.0f;
        if (l == 0) {
            survive[i] = m;
            cnt += (m != 0.0f) ? 1 : 0;
        }
    }
    __shared__ int sc[8];
    if (l == 0) sc[s] = cnt;
    __syncthreads();
    if (threadIdx.x == 0) {
        int t = 0;
#pragma unroll
        for (int k = 0; k < 8; k++) t += sc[k];
        dinvM[v] = 1.0f / sqrtf((float)t + 1.0f);
    }
}

// pack W -> 3 bf16 split planes
__device__ inline void packw3_one(const float* __restrict__ W, unsigned short* __restrict__ Wp,
                                  int OUTC, int idx) {
    int l = idx & 63;
    int tk = idx >> 6;
    int kb = tk & 3;
    int ct = tk >> 2;
    size_t PL = (size_t)(OUTC / 16) * 4 * 64 * 8;
    unsigned short v0[8], v1[8], v2[8];
#pragma unroll
    for (int i = 0; i < 8; i++) {
        float wv = W[(kb * 32 + ((l >> 4) * 8) + i) * OUTC + ct * 16 + (l & 15)];
        unsigned short h0 = bf1(wv);
        float f0 = __uint_as_float((unsigned)h0 << 16);
        float r1 = wv - f0;
        unsigned short h1 = bf1(r1);
        float f1 = __uint_as_float((unsigned)h1 << 16);
        unsigned short h2 = bf1(r1 - f1);
        v0[i] = h0; v1[i] = h1; v2[i] = h2;
    }
    auto st = [](unsigned short* dst, unsigned short* v) {
        uint4 u;
        u.x = v[0] | ((unsigned)v[1] << 16);
        u.y = v[2] | ((unsigned)v[3] << 16);
        u.z = v[4] | ((unsigned)v[5] << 16);
        u.w = v[6] | ((unsigned)v[7] << 16);
        *(uint4*)dst = u;
    };
    st(&Wp[(size_t)idx * 8], v0);
    st(&Wp[PL + (size_t)idx * 8], v1);
    st(&Wp[2 * PL + (size_t)idx * 8], v2);
}

__global__ void k_packw3_all(const float* __restrict__ w0, const float* __restrict__ w1,
                             const float* __restrict__ w2,
                             unsigned short* __restrict__ w0p, unsigned short* __restrict__ w1p,
                             unsigned short* __restrict__ w2p) {
    int b = blockIdx.x;
    if (b < 8) packw3_one(w0, w0p, 128, b * 256 + threadIdx.x);
    else if (b < 16) packw3_one(w1, w1p, 128, (b - 8) * 256 + threadIdx.x);
    else packw3_one(w2, w2p, 64, (b - 16) * 256 + threadIdx.x);
}

// split-bf16 MFMA GEMM (pass 1). A: normal layout if !ASL, sliced if ASL.
// Outputs sliced: Cout f32 [OUTC/16][N][16], Cb bf16 same geometry.
template <int OUTC, bool WB16, bool ASL>
__global__ __launch_bounds__(256) void k_gemm_split(const float* __restrict__ A,
                                                    const unsigned short* __restrict__ Wp,
                                                    float* __restrict__ Cout,
                                                    unsigned short* __restrict__ Cb, int N) {
    constexpr int CT = OUTC / 16;
    constexpr int PL = CT * 4 * 64 * 8;
    constexpr int LDW = OUTC + 4;
    __shared__ float eps[64 * LDW];
    const int w = threadIdx.x >> 6;
    const int l = threadIdx.x & 63;
    int row = blockIdx.x * 64 + w * 16 + (l & 15);
    int rowc = (row < N) ? row : (N - 1);

    bf16x8 a0[4], a1[4], a2[4];
#pragma unroll
    for (int kb = 0; kb < 4; kb++) {
        int col0 = kb * 32 + ((l >> 4) * 8);
        const float* pa = ASL ? &A[((size_t)(col0 >> 4) * N + rowc) * 16 + (col0 & 15)]
                              : &A[(size_t)rowc * 128 + col0];
        float4 x0 = *(const float4*)pa;
        float4 x1 = *(const float4*)(pa + 4);
        float xa[8] = {x0.x, x0.y, x0.z, x0.w, x1.x, x1.y, x1.z, x1.w};
#pragma unroll
        for (int i = 0; i < 8; i++) {
            unsigned short h0 = bf1(xa[i]);
            float f0 = __uint_as_float((unsigned)h0 << 16);
            float r1 = xa[i] - f0;
            unsigned short h1 = bf1(r1);
            float f1 = __uint_as_float((unsigned)h1 << 16);
            unsigned short h2 = bf1(r1 - f1);
            a0[kb][i] = (short)h0;
            a1[kb][i] = (short)h1;
            a2[kb][i] = (short)h2;
        }
    }
#pragma unroll
    for (int ct = 0; ct < CT; ct++) {
        f32x4 accA = {0.f, 0.f, 0.f, 0.f};
        f32x4 accB = {0.f, 0.f, 0.f, 0.f};
#pragma unroll
        for (int kb = 0; kb < 4; kb++) {
            const size_t bo = ((size_t)(ct * 4 + kb) * 64 + l) * 8;
            bf16x8 b0 = *(const bf16x8*)&Wp[bo];
            bf16x8 b1 = *(const bf16x8*)&Wp[PL + bo];
            bf16x8 b2 = *(const bf16x8*)&Wp[2 * PL + bo];
            accA = __builtin_amdgcn_mfma_f32_16x16x32_bf16(a0[kb], b0, accA, 0, 0, 0);
            accB = __builtin_amdgcn_mfma_f32_16x16x32_bf16(a0[kb], b1, accB, 0, 0, 0);
            accA = __builtin_amdgcn_mfma_f32_16x16x32_bf16(a1[kb], b0, accA, 0, 0, 0);
            accB = __builtin_amdgcn_mfma_f32_16x16x32_bf16(a1[kb], b1, accB, 0, 0, 0);
            accA = __builtin_amdgcn_mfma_f32_16x16x32_bf16(a2[kb], b0, accA, 0, 0, 0);
            accB = __builtin_amdgcn_mfma_f32_16x16x32_bf16(a0[kb], b2, accB, 0, 0, 0);
        }
#pragma unroll
        for (int r = 0; r < 4; r++) {
            int rr = w * 16 + (l >> 4) * 4 + r;
            eps[rr * LDW + ct * 16 + (l & 15)] = accA[r] + accB[r];
        }
    }
    __syncthreads();
    constexpr int NF4 = 64 * OUTC / 4;
    for (int idx = threadIdx.x; idx < NF4; idx += 256) {
        int rl = idx / (OUTC / 4);
        int cg = idx % (OUTC / 4);
        int grow = blockIdx.x * 64 + rl;
        if (grow < N) {
            const float* sp = &eps[rl * LDW + cg * 4];
            float4 vv = make_float4(sp[0], sp[1], sp[2], sp[3]);
            int col0 = cg * 4;
            size_t ad = ((size_t)(col0 >> 4) * N + grow) * 16 + (col0 & 15);
            *(float4*)&Cout[ad] = vv;
            if (WB16)
                *(uint2*)&Cb[ad] = make_uint2(bfpair(vv.x, vv.y), bfpair(vv.z, vv.w));
        }
    }
}

// plain bf16 MFMA GEMM (pass 2): A bf16 sliced, out bf16 sliced.
template <int OUTC>
__global__ __launch_bounds__(256) void k_gemm_mfma(const unsigned short* __restrict__ A,
                                                   const unsigned short* __restrict__ Wpk,
                                                   unsigned short* __restrict__ C, int N) {
    constexpr int CT = OUTC / 16;
    __shared__ unsigned short eps[64 * OUTC];
    const int w = threadIdx.x >> 6;
    const int l = threadIdx.x & 63;
    int row = blockIdx.x * 64 + (w * 16) + (l & 15);
    int rowc = (row < N) ? row : (N - 1);

    bf16x8 a[4];
#pragma unroll
    for (int kb = 0; kb < 4; kb++) {
        int col0 = kb * 32 + ((l >> 4) * 8);
        a[kb] = *(const bf16x8*)&A[((size_t)(col0 >> 4) * N + rowc) * 16 + (col0 & 15)];
    }
#pragma unroll
    for (int ct = 0; ct < CT; ct++) {
        f32x4 acc = {0.f, 0.f, 0.f, 0.f};
#pragma unroll
        for (int kb = 0; kb < 4; kb++) {
            bf16x8 b = *(const bf16x8*)&Wpk[((size_t)(ct * 4 + kb) * 64 + l) * 8];
            acc = __builtin_amdgcn_mfma_f32_16x16x32_bf16(a[kb], b, acc, 0, 0, 0);
        }
#pragma unroll
        for (int r = 0; r < 4; r++) {
            int rr = w * 16 + (l >> 4) * 4 + r;
            eps[rr * OUTC + ct * 16 + (l & 15)] = bf1(acc[r]);
        }
    }
    __syncthreads();
    constexpr int NU4 = 64 * OUTC / 8;
    for (int idx = threadIdx.x; idx < NU4; idx += 256) {
        int rl = idx / (OUTC / 8);
        int cg = idx % (OUTC / 8);
        int grow = blockIdx.x * 64 + rl;
        if (grow < N) {
            size_t ad = ((size_t)(cg >> 1) * N + grow) * 16 + (cg & 1) * 8;
            *(uint4*)&C[ad] = *(const uint4*)&eps[rl * OUTC + cg * 8];
        }
    }
}

// ---- sliced f32 aggregation (pass 1): slice = blockIdx & (NSL-1) -> XCD ----
// wave = node; 16 edge slots x 4 lanes (float4 = 16B; 4 lanes = 64B slice row).
template <int NSL, bool RELU, bool TZOUT>
__global__ __launch_bounds__(256) void k_aggs(const float* __restrict__ hs,
                                              const int* __restrict__ csr_off,
                                              const int2* __restrict__ csr_se,
                                              const float* __restrict__ dinv,
                                              const float* __restrict__ bias,
                                              float* __restrict__ outp, int N) {
    const int s = blockIdx.x & (NSL - 1);
    const int v = (blockIdx.x / NSL) * 4 + (threadIdx.x >> 6);
    if (v >= N) return;
    const int lane = threadIdx.x & 63;
    const int fl = lane & 3;
    const int slot = lane >> 2;     // 0..15
    const int e0 = csr_off[v];
    const int e1 = csr_off[v + 1];
    const size_t sb = (size_t)s * N;
    float4 acc = make_float4(0.f, 0.f, 0.f, 0.f);
    for (int i = e0 + slot; i < e1; i += 16) {
        int sa = csr_se[i].x;
        float wa = dinv[sa];
        float4 a = *(const float4*)&hs[(sb + sa) * 16 + fl * 4];
        acc.x = fmaf(a.x, wa, acc.x); acc.y = fmaf(a.y, wa, acc.y);
        acc.z = fmaf(a.z, wa, acc.z); acc.w = fmaf(a.w, wa, acc.w);
    }
    acc.x += __shfl_xor(acc.x, 4);  acc.y += __shfl_xor(acc.y, 4);
    acc.z += __shfl_xor(acc.z, 4);  acc.w += __shfl_xor(acc.w, 4);
    acc.x += __shfl_xor(acc.x, 8);  acc.y += __shfl_xor(acc.y, 8);
    acc.z += __shfl_xor(acc.z, 8);  acc.w += __shfl_xor(acc.w, 8);
    acc.x += __shfl_xor(acc.x, 16); acc.y += __shfl_xor(acc.y, 16);
    acc.z += __shfl_xor(acc.z, 16); acc.w += __shfl_xor(acc.w, 16);
    acc.x += __shfl_xor(acc.x, 32); acc.y += __shfl_xor(acc.y, 32);
    acc.z += __shfl_xor(acc.z, 32); acc.w += __shfl_xor(acc.w, 32);
    if (slot == 0) {
        float dv = dinv[v];
        float4 hv = *(const float4*)&hs[(sb + v) * 16 + fl * 4];
        float4 bb = *(const float4*)&bias[s * 16 + fl * 4];
        float4 o;
        o.x = dv * (acc.x + hv.x * dv) + bb.x;
        o.y = dv * (acc.y + hv.y * dv) + bb.y;
        o.z = dv * (acc.z + hv.z * dv) + bb.z;
        o.w = dv * (acc.w + hv.w * dv) + bb.w;
        if (RELU) {
            o.x = fmaxf(o.x, 0.f); o.y = fmaxf(o.y, 0.f);
            o.z = fmaxf(o.z, 0.f); o.w = fmaxf(o.w, 0.f);
        }
        if (TZOUT)  // normal layout [N][NSL*16] (tz, consumed row-wise by k_surv)
            *(float4*)&outp[(size_t)v * (NSL * 16) + s * 16 + fl * 4] = o;
        else        // sliced layout
            *(float4*)&outp[(sb + v) * 16 + fl * 4] = o;
    }
}

// ---- sliced bf16 aggregation (pass 2): 16 slots x 4 lanes (uint2 = 4 bf16) --
template <int NSL, bool RELU, bool MASKED, bool F32OUT>
__global__ __launch_bounds__(256) void k_aggsb(const unsigned short* __restrict__ hs,
                                               const int* __restrict__ csr_off,
                                               const int2* __restrict__ csr_se,
                                               const float* __restrict__ survive,
                                               const float* __restrict__ dinv,
                                               const float* __restrict__ bias,
                                               void* __restrict__ outp, int N) {
    const int s = blockIdx.x & (NSL - 1);
    const int v = (blockIdx.x / NSL) * 4 + (threadIdx.x >> 6);
    if (v >= N) return;
    const int lane = threadIdx.x & 63;
    const int fl = lane & 3;
    const int slot = lane >> 2;     // 0..15
    const int e0 = csr_off[v];
    const int e1 = csr_off[v + 1];
    const size_t sb = (size_t)s * N;
    float acc[4] = {0.f, 0.f, 0.f, 0.f};
    for (int i = e0 + slot; i < e1; i += 16) {
        int sa = csr_se[i].x;
        float wa = MASKED ? dinv[sa] * survive[i] : dinv[sa];
        uint2 ua = *(const uint2*)&hs[(sb + sa) * 16 + fl * 4];
        float f0, f1;
        unpack2(ua.x, f0, f1); acc[0] = fmaf(f0, wa, acc[0]); acc[1] = fmaf(f1, wa, acc[1]);
        unpack2(ua.y, f0, f1); acc[2] = fmaf(f0, wa, acc[2]); acc[3] = fmaf(f1, wa, acc[3]);
    }
#pragma unroll
    for (int j = 0; j < 4; j++) acc[j] += __shfl_xor(acc[j], 4);
#pragma unroll
    for (int j = 0; j < 4; j++) acc[j] += __shfl_xor(acc[j], 8);
#pragma unroll
    for (int j = 0; j < 4; j++) acc[j] += __shfl_xor(acc[j], 16);
#pragma unroll
    for (int j = 0; j < 4; j++) acc[j] += __shfl_xor(acc[j], 32);
    if (slot == 0) {
        float dv = dinv[v];
        uint2 uh = *(const uint2*)&hs[(sb + v) * 16 + fl * 4];
        float hv[4];
        unpack2(uh.x, hv[0], hv[1]);
        unpack2(uh.y, hv[2], hv[3]);
        float o[4];
#pragma unroll
        for (int j = 0; j < 4; j++) {
            o[j] = dv * (acc[j] + hv[j] * dv) + bias[s * 16 + fl * 4 + j];
            if (RELU) o[j] = fmaxf(o[j], 0.f);
        }
        if (F32OUT) {   // final layer: normal f32 layout [N][NSL*16]
            *(float4*)&((float*)outp)[(size_t)v * (NSL * 16) + s * 16 + fl * 4] =
                make_float4(o[0], o[1], o[2], o[3]);
        } else {        // sliced bf16
            *(uint2*)&((unsigned short*)outp)[(sb + v) * 16 + fl * 4] =
                make_uint2(bfpair(o[0], o[1]), bfpair(o[2], o[3]));
        }
    }
}

extern "C" void kernel_launch(void* const* d_in, const int* in_sizes, int n_in,
                              void* d_out, int out_size, void* d_ws, size_t ws_size,
                              hipStream_t stream) {
    const float* x  = (const float*)d_in[0];
    const int*   ei = (const int*)d_in[1];
    const float* er = (const float*)d_in[2];
    const float* w0 = (const float*)d_in[3];
    const float* b0 = (const float*)d_in[4];
    const float* w1 = (const float*)d_in[5];
    const float* b1 = (const float*)d_in[6];
    const float* w2 = (const float*)d_in[7];
    const float* b2 = (const float*)d_in[8];
    const int N = in_sizes[0] / 128;
    const int E = in_sizes[2];
    const int* src  = ei;
    const int* dstv = ei + E;
    float* out = (float*)d_out;

    // workspace carve
    char* p = (char*)d_ws;
    auto alloc = [&](size_t bytes) {
        char* r = p;
        p += (bytes + 255) & ~(size_t)255;
        return r;
    };
    int* indeg     = (int*)alloc((size_t)N * 4);
    int* csr_off   = (int*)alloc((size_t)(N + 1) * 4);
    int* bsums     = (int*)alloc(1024);
    int* bcnt      = (int*)alloc((size_t)65536 * 4);
    int* sbase     = (int*)alloc((size_t)65537 * 4);
    int2* csr_se   = (int2*)alloc((size_t)E * 8);
    int2* stg      = (int2*)alloc((size_t)E * 8);   // staging; survive aliases
    float* dinvF   = (float*)alloc((size_t)N * 4);
    float* dinvM   = (float*)alloc((size_t)N * 4);
    float* hx      = (float*)alloc((size_t)N * 128 * 4);   // sliced [8][N][16]
    unsigned short* hxb = (unsigned short*)alloc((size_t)N * 128 * 2);  // sliced
    float* wk1     = (float*)alloc((size_t)N * 128 * 4);   // sliced
    float* wk2     = (float*)alloc((size_t)N * 128 * 4);   // sliced
    float* tz      = (float*)alloc((size_t)N * 64 * 4);    // NORMAL layout
    unsigned short* w0p3 = (unsigned short*)alloc((size_t)3 * 128 * 128 * 2);
    unsigned short* w1p3 = (unsigned short*)alloc((size_t)3 * 128 * 128 * 2);
    unsigned short* w2p3 = (unsigned short*)alloc((size_t)3 * 128 * 64 * 2);
    unsigned short* wk1b = (unsigned short*)wk1;
    unsigned short* wk2b = (unsigned short*)wk2;
    float* survive = (float*)stg;                 // stg dead after k_bfill

    const int nb = (N + 255) / 256;
    const int chunk = (E + 63) / 64;

    k_packw3_all<<<20, 256, 0, stream>>>(w0, w1, w2, w0p3, w1p3, w2p3);

    // ---- bucket-radix CSR build ----
    k_bcount<<<64, 256, 0, stream>>>(dstv, bcnt, E, chunk);
    k_scan1<<<256, 256, 0, stream>>>(bcnt, sbase, bsums, 65536);
    k_scan2<<<1, 256, 0, stream>>>(bsums, 256);
    k_scan3<<<256, 256, 0, stream>>>(sbase, bsums, 65536, E);
    k_bscatter<<<64, 256, 0, stream>>>(src, dstv, er, sbase, stg, E, chunk);
    k_bindeg<<<1024, 256, 0, stream>>>(stg, sbase, indeg, dinvF, N);
    k_scan1<<<nb, 256, 0, stream>>>(indeg, csr_off, bsums, N);
    k_scan2<<<1, 256, 0, stream>>>(bsums, nb);
    k_scan3<<<nb, 256, 0, stream>>>(csr_off, bsums, N, E);
    k_bfill<<<1024, 256, 0, stream>>>(stg, sbase, csr_off, csr_se, N);

    const int gbm = (N + 63) / 64;
    const int gn4 = (N + 3) / 4;
    const int ga8 = gn4 * 8;
    const int ga4 = gn4 * 4;

    // shared first GEMM (A = x, normal layout): f32 sliced + bf16 sliced
    k_gemm_split<128, true, false><<<gbm, 256, 0, stream>>>(x, w0p3, hx, hxb, N);

    // pass 1 (full graph, near-exact -> tz -> mask)
    k_aggs<8, true, false><<<ga8, 256, 0, stream>>>(hx, csr_off, csr_se, dinvF, b0, wk1, N);
    k_gemm_split<128, false, true><<<gbm, 256, 0, stream>>>(wk1, w1p3, wk2, nullptr, N);
    k_aggs<8, true, false><<<ga8, 256, 0, stream>>>(wk2, csr_off, csr_se, dinvF, b1, wk1, N);
    k_gemm_split<64, false, true><<<gbm, 256, 0, stream>>>(wk1, w2p3, wk2, nullptr, N);
    k_aggs<4, false, true><<<ga4, 256, 0, stream>>>(wk2, csr_off, csr_se, dinvF, b2, tz, N);

    // edge sampling (tz normal layout)
    k_surv<<<N, 128, 0, stream>>>(tz, csr_off, csr_se, survive, dinvM, N);

    // pass 2 (post-mask: sliced bf16 aggs + bf16 MFMA GEMMs)
    k_aggsb<8, true, true, false><<<ga8, 256, 0, stream>>>(hxb, csr_off, csr_se, survive, dinvM, b0, wk1b, N);
    k_gemm_mfma<128><<<gbm, 256, 0, stream>>>(wk1b, w1p3, wk2b, N);
    k_aggsb<8, true, true, false><<<ga8, 256, 0, stream>>>(wk2b, csr_off, csr_se, survive, dinvM, b1, wk1b, N);
    k_gemm_mfma<64><<<gbm, 256, 0, stream>>>(wk1b, w2p3, wk2b, N);
    k_aggsb<4, false, false, true><<<ga4, 256, 0, stream>>>(wk2b, csr_off, csr_se, survive, dinvF, b2, out, N);
}

// Round 11
// 461.509 us; speedup vs baseline: 1.7813x; 1.7813x over previous
//
#include <hip/hip_runtime.h>

// ---------------------------------------------------------------------------
// GCN with edge sampling.  (R9 structure restored; k_surv wave-per-node.)
//  Pass 1 (-> tz -> mask) uses split-bf16 MFMA GEMMs (3-plane Ozaki split,
//  6 cross terms, error ~2^-26) + exact f32 aggs -> mask bit-stable.
//  Pass 2 (post-mask) is bf16 end-to-end.
//  CSR build: bucket-radix (bucket = dst>>6), LDS atomics only.
//  Aggregations: wave-per-node, no LDS, no barriers (shfl_xor reduction).
// conv: out[v] = dinv[v]*(sum_e h[src]*dinv[src]*m[e] + h[v]*dinv[v]) + b
// ---------------------------------------------------------------------------

typedef __attribute__((ext_vector_type(8))) short bf16x8;
typedef __attribute__((ext_vector_type(4))) float f32x4;

__device__ inline unsigned bfpair(float lo, float hi) {   // pack 2 f32 -> bf16x2 RNE
    unsigned a = __float_as_uint(lo), b = __float_as_uint(hi);
    a = (a + 0x7FFFu + ((a >> 16) & 1u)) >> 16;
    b = (b + 0x7FFFu + ((b >> 16) & 1u)) & 0xFFFF0000u;
    return a | b;
}
__device__ inline unsigned short bf1(float v) {
    unsigned u = __float_as_uint(v);
    return (unsigned short)((u + 0x7FFFu + ((u >> 16) & 1u)) >> 16);
}
__device__ inline void unpack2(unsigned u, float& f0, float& f1) {
    f0 = __uint_as_float(u << 16);
    f1 = __uint_as_float(u & 0xFFFF0000u);
}

// ---------------- scans (generic, 256-wide) ----------------
__global__ void k_scan1(const int* __restrict__ in, int* __restrict__ out,
                        int* __restrict__ bsums, int N) {
    __shared__ int tmp[256];
    int i = blockIdx.x * 256 + threadIdx.x;
    int v = (i < N) ? in[i] : 0;
    tmp[threadIdx.x] = v;
    __syncthreads();
    for (int off = 1; off < 256; off <<= 1) {
        int t = (threadIdx.x >= off) ? tmp[threadIdx.x - off] : 0;
        __syncthreads();
        tmp[threadIdx.x] += t;
        __syncthreads();
    }
    if (i < N) out[i] = tmp[threadIdx.x] - v;   // exclusive
    if (threadIdx.x == 255) bsums[blockIdx.x] = tmp[255];
}

__global__ void k_scan2(int* __restrict__ bsums, int nb) {
    __shared__ int tmp[256];
    int v = (threadIdx.x < nb) ? bsums[threadIdx.x] : 0;
    tmp[threadIdx.x] = v;
    __syncthreads();
    for (int off = 1; off < 256; off <<= 1) {
        int t = (threadIdx.x >= off) ? tmp[threadIdx.x - off] : 0;
        __syncthreads();
        tmp[threadIdx.x] += t;
        __syncthreads();
    }
    if (threadIdx.x < nb) bsums[threadIdx.x] = tmp[threadIdx.x] - v;  // exclusive
}

__global__ void k_scan3(int* __restrict__ out, const int* __restrict__ bsums, int N, int E) {
    int i = blockIdx.x * 256 + threadIdx.x;
    if (i < N) out[i] += bsums[blockIdx.x];
    if (i == 0) out[N] = E;
}

// ---------------- bucket-radix CSR build (no global atomics) ----------------
__global__ __launch_bounds__(256) void k_bcount(const int* __restrict__ dst,
                                                int* __restrict__ cnt, int E, int chunk) {
    __shared__ int h[1024];
    for (int i = threadIdx.x; i < 1024; i += 256) h[i] = 0;
    __syncthreads();
    int beg = blockIdx.x * chunk, end = min(E, beg + chunk);
    for (int e = beg + threadIdx.x; e < end; e += 256)
        atomicAdd(&h[dst[e] >> 6], 1);
    __syncthreads();
    for (int b = threadIdx.x; b < 1024; b += 256)
        cnt[b * 64 + blockIdx.x] = h[b];
}

// staging payload: .x = src | (dst&63)<<16  (src < 65536), .y = er bits
__global__ __launch_bounds__(256) void k_bscatter(const int* __restrict__ src,
                                                  const int* __restrict__ dst,
                                                  const float* __restrict__ er,
                                                  const int* __restrict__ sbase,
                                                  int2* __restrict__ stg, int E, int chunk) {
    __shared__ int cur[1024];
    for (int i = threadIdx.x; i < 1024; i += 256) cur[i] = 0;
    __syncthreads();
    int beg = blockIdx.x * chunk, end = min(E, beg + chunk);
    for (int e = beg + threadIdx.x; e < end; e += 256) {
        int d = dst[e];
        int b = d >> 6;
        int loc = atomicAdd(&cur[b], 1);
        int pos = sbase[b * 64 + blockIdx.x] + loc;
        stg[pos] = make_int2(src[e] | ((d & 63) << 16), (int)__float_as_uint(er[e]));
    }
}

// per-bucket indeg + dinvF (k_dinv folded in)
__global__ __launch_bounds__(256) void k_bindeg(const int2* __restrict__ stg,
                                                const int* __restrict__ sbase,
                                                int* __restrict__ indeg,
                                                float* __restrict__ dinvF, int N) {
    __shared__ int cnt[64];
    if (threadIdx.x < 64) cnt[threadIdx.x] = 0;
    __syncthreads();
    int b = blockIdx.x;
    int beg = sbase[b * 64], end = sbase[(b + 1) * 64];
    for (int i = beg + threadIdx.x; i < end; i += 256)
        atomicAdd(&cnt[(stg[i].x >> 16) & 63], 1);
    __syncthreads();
    if (threadIdx.x < 64) {
        int node = b * 64 + threadIdx.x;
        if (node < N) {
            int c = cnt[threadIdx.x];
            indeg[node] = c;
            dinvF[node] = 1.0f / sqrtf((float)c + 1.0f);
        }
    }
}

// bucket owns its 64 dst nodes exclusively -> LDS cursors give unique slots.
__global__ __launch_bounds__(256) void k_bfill(const int2* __restrict__ stg,
                                               const int* __restrict__ sbase,
                                               const int* __restrict__ csr_off,
                                               int2* __restrict__ csr_se, int N) {
    __shared__ int cur[64];
    int b = blockIdx.x;
    if (threadIdx.x < 64) {
        int node = b * 64 + threadIdx.x;
        cur[threadIdx.x] = (node < N) ? csr_off[node] : 0;
    }
    __syncthreads();
    int beg = sbase[b * 64], end = sbase[(b + 1) * 64];
    for (int i = beg + threadIdx.x; i < end; i += 256) {
        int2 se = stg[i];
        int j = (se.x >> 16) & 63;
        int pos = atomicAdd(&cur[j], 1);
        csr_se[pos] = make_int2(se.x & 0xFFFF, se.y);
    }
}

// mask in CSR order: wave-per-node (4 nodes/block), 4 slots x 16 lanes.
// per-edge dot: same 16-lane shfl order as before -> bit-identical mask.
__global__ __launch_bounds__(256) void k_surv(const float* __restrict__ tz,
                                              const int* __restrict__ csr_off,
                                              const int2* __restrict__ csr_se,
                                              float* __restrict__ survive,
                                              float* __restrict__ dinvM, int N) {
    const int v = blockIdx.x * 4 + (threadIdx.x >> 6);
    if (v >= N) return;
    const int lane = threadIdx.x & 63;
    const int l = lane & 15;
    const int s = lane >> 4;        // 0..3 edge slot
    const int e0 = csr_off[v];
    const int e1 = csr_off[v + 1];
    const float4 tv = *(const float4*)&tz[(size_t)v * 64 + l * 4];
    int cnt = 0;
    for (int i = e0 + s; i < e1; i += 4) {
        int2 se = csr_se[i];
        const float4 a = *(const float4*)&tz[(size_t)se.x * 64 + l * 4];
        float p = a.x * tv.x + a.y * tv.y + a.z * tv.z + a.w * tv.w;
        p += __shfl_xor(p, 1, 16);
        p += __shfl_xor(p, 2, 16);
        p += __shfl_xor(p, 4, 16);
        p += __shfl_xor(p, 8, 16);
        float sg = 1.0f / (1.0f + expf(-p));
        float m = (sg > __uint_as_float((unsigned)se.y)) ? 1.0f : 0.0f;
        if (l == 0) {
            survive[i] = m;
            cnt += (m != 0.0f) ? 1 : 0;
        }
    }
    cnt += __shfl_xor(cnt, 16);     // cnt nonzero only at l==0 lanes
    cnt += __shfl_xor(cnt, 32);
    if (lane == 0) dinvM[v] = 1.0f / sqrtf((float)cnt + 1.0f);
}

// pack W -> 3 bf16 split planes (plane 0 = bf16(W), reused by pass-2 GEMMs)
__device__ inline void packw3_one(const float* __restrict__ W, unsigned short* __restrict__ Wp,
                                  int OUTC, int idx) {
    int l = idx & 63;
    int tk = idx >> 6;
    int kb = tk & 3;
    int ct = tk >> 2;
    size_t PL = (size_t)(OUTC / 16) * 4 * 64 * 8;
    unsigned short v0[8], v1[8], v2[8];
#pragma unroll
    for (int i = 0; i < 8; i++) {
        float wv = W[(kb * 32 + ((l >> 4) * 8) + i) * OUTC + ct * 16 + (l & 15)];
        unsigned short h0 = bf1(wv);
        float f0 = __uint_as_float((unsigned)h0 << 16);
        float r1 = wv - f0;
        unsigned short h1 = bf1(r1);
        float f1 = __uint_as_float((unsigned)h1 << 16);
        unsigned short h2 = bf1(r1 - f1);
        v0[i] = h0; v1[i] = h1; v2[i] = h2;
    }
    auto st = [](unsigned short* dst, unsigned short* v) {
        uint4 u;
        u.x = v[0] | ((unsigned)v[1] << 16);
        u.y = v[2] | ((unsigned)v[3] << 16);
        u.z = v[4] | ((unsigned)v[5] << 16);
        u.w = v[6] | ((unsigned)v[7] << 16);
        *(uint4*)dst = u;
    };
    st(&Wp[(size_t)idx * 8], v0);
    st(&Wp[PL + (size_t)idx * 8], v1);
    st(&Wp[2 * PL + (size_t)idx * 8], v2);
}

__global__ void k_packw3_all(const float* __restrict__ w0, const float* __restrict__ w1,
                             const float* __restrict__ w2,
                             unsigned short* __restrict__ w0p, unsigned short* __restrict__ w1p,
                             unsigned short* __restrict__ w2p) {
    int b = blockIdx.x;
    if (b < 8) packw3_one(w0, w0p, 128, b * 256 + threadIdx.x);
    else if (b < 16) packw3_one(w1, w1p, 128, (b - 8) * 256 + threadIdx.x);
    else packw3_one(w2, w2p, 64, (b - 16) * 256 + threadIdx.x);
}

// split-bf16 MFMA GEMM (pass 1): 6 cross terms (00,10,20 | 01,11,02),
// error ~2^-26. f32 out (+ optional bf16 copy).
template <int OUTC, bool WB16>
__global__ __launch_bounds__(256) void k_gemm_split(const float* __restrict__ A,
                                                    const unsigned short* __restrict__ Wp,
                                                    float* __restrict__ Cout,
                                                    unsigned short* __restrict__ Cb, int N) {
    constexpr int CT = OUTC / 16;
    constexpr int PL = CT * 4 * 64 * 8;
    constexpr int LDW = OUTC + 4;
    __shared__ float eps[64 * LDW];
    const int w = threadIdx.x >> 6;
    const int l = threadIdx.x & 63;
    int row = blockIdx.x * 64 + w * 16 + (l & 15);
    int rowc = (row < N) ? row : (N - 1);

    bf16x8 a0[4], a1[4], a2[4];
#pragma unroll
    for (int kb = 0; kb < 4; kb++) {
        const float* pa = &A[(size_t)rowc * 128 + kb * 32 + ((l >> 4) * 8)];
        float4 x0 = *(const float4*)pa;
        float4 x1 = *(const float4*)(pa + 4);
        float xa[8] = {x0.x, x0.y, x0.z, x0.w, x1.x, x1.y, x1.z, x1.w};
#pragma unroll
        for (int i = 0; i < 8; i++) {
            unsigned short h0 = bf1(xa[i]);
            float f0 = __uint_as_float((unsigned)h0 << 16);
            float r1 = xa[i] - f0;
            unsigned short h1 = bf1(r1);
            float f1 = __uint_as_float((unsigned)h1 << 16);
            unsigned short h2 = bf1(r1 - f1);
            a0[kb][i] = (short)h0;
            a1[kb][i] = (short)h1;
            a2[kb][i] = (short)h2;
        }
    }
#pragma unroll
    for (int ct = 0; ct < CT; ct++) {
        f32x4 accA = {0.f, 0.f, 0.f, 0.f};
        f32x4 accB = {0.f, 0.f, 0.f, 0.f};
#pragma unroll
        for (int kb = 0; kb < 4; kb++) {
            const size_t bo = ((size_t)(ct * 4 + kb) * 64 + l) * 8;
            bf16x8 b0 = *(const bf16x8*)&Wp[bo];
            bf16x8 b1 = *(const bf16x8*)&Wp[PL + bo];
            bf16x8 b2 = *(const bf16x8*)&Wp[2 * PL + bo];
            accA = __builtin_amdgcn_mfma_f32_16x16x32_bf16(a0[kb], b0, accA, 0, 0, 0);
            accB = __builtin_amdgcn_mfma_f32_16x16x32_bf16(a0[kb], b1, accB, 0, 0, 0);
            accA = __builtin_amdgcn_mfma_f32_16x16x32_bf16(a1[kb], b0, accA, 0, 0, 0);
            accB = __builtin_amdgcn_mfma_f32_16x16x32_bf16(a1[kb], b1, accB, 0, 0, 0);
            accA = __builtin_amdgcn_mfma_f32_16x16x32_bf16(a2[kb], b0, accA, 0, 0, 0);
            accB = __builtin_amdgcn_mfma_f32_16x16x32_bf16(a0[kb], b2, accB, 0, 0, 0);
        }
        // C/D map: col = lane&15, row = (lane>>4)*4 + r  [HW-verified]
#pragma unroll
        for (int r = 0; r < 4; r++) {
            int rr = w * 16 + (l >> 4) * 4 + r;
            eps[rr * LDW + ct * 16 + (l & 15)] = accA[r] + accB[r];
        }
    }
    __syncthreads();
    constexpr int NF4 = 64 * OUTC / 4;
    for (int idx = threadIdx.x; idx < NF4; idx += 256) {
        int rl = idx / (OUTC / 4);
        int cg = idx % (OUTC / 4);
        int grow = blockIdx.x * 64 + rl;
        if (grow < N) {
            const float* sp = &eps[rl * LDW + cg * 4];
            float4 vv = make_float4(sp[0], sp[1], sp[2], sp[3]);
            *(float4*)&Cout[(size_t)grow * OUTC + cg * 4] = vv;
            if (WB16)
                *(uint2*)&Cb[(size_t)grow * OUTC + cg * 4] =
                    make_uint2(bfpair(vv.x, vv.y), bfpair(vv.z, vv.w));
        }
    }
}

// plain bf16 MFMA GEMM (pass 2): A bf16, Wpk = plane 0 of packw3, bf16 out.
template <int OUTC>
__global__ __launch_bounds__(256) void k_gemm_mfma(const unsigned short* __restrict__ A,
                                                   const unsigned short* __restrict__ Wpk,
                                                   unsigned short* __restrict__ C, int N) {
    constexpr int CT = OUTC / 16;
    __shared__ unsigned short eps[64 * OUTC];
    const int w = threadIdx.x >> 6;
    const int l = threadIdx.x & 63;
    const int rowl = (w * 16) + (l & 15);
    int row = blockIdx.x * 64 + rowl;
    int rowc = (row < N) ? row : (N - 1);

    bf16x8 a[4];
#pragma unroll
    for (int kb = 0; kb < 4; kb++)
        a[kb] = *(const bf16x8*)&A[(size_t)rowc * 128 + kb * 32 + ((l >> 4) * 8)];

#pragma unroll
    for (int ct = 0; ct < CT; ct++) {
        f32x4 acc = {0.f, 0.f, 0.f, 0.f};
#pragma unroll
        for (int kb = 0; kb < 4; kb++) {
            bf16x8 b = *(const bf16x8*)&Wpk[((size_t)(ct * 4 + kb) * 64 + l) * 8];
            acc = __builtin_amdgcn_mfma_f32_16x16x32_bf16(a[kb], b, acc, 0, 0, 0);
        }
#pragma unroll
        for (int r = 0; r < 4; r++) {
            int rr = w * 16 + (l >> 4) * 4 + r;
            eps[rr * OUTC + ct * 16 + (l & 15)] = bf1(acc[r]);
        }
    }
    __syncthreads();
    constexpr int NU4 = 64 * OUTC / 8;
    for (int idx = threadIdx.x; idx < NU4; idx += 256) {
        int rl = idx / (OUTC / 8);
        int cg = idx % (OUTC / 8);
        int grow = blockIdx.x * 64 + rl;
        if (grow < N)
            *(uint4*)&C[(size_t)grow * OUTC + cg * 8] = *(const uint4*)&eps[rl * OUTC + cg * 8];
    }
}

// -------- fp32 aggregations (pass 1, mask-critical), wave-per-node ---------
template <bool RELU>
__global__ __launch_bounds__(256) void k_agg128(const float* __restrict__ h,
                                                const int* __restrict__ csr_off,
                                                const int2* __restrict__ csr_se,
                                                const float* __restrict__ dinv,
                                                const float* __restrict__ bias,
                                                float* __restrict__ out, int N) {
    const int v = blockIdx.x * 4 + (threadIdx.x >> 6);
    if (v >= N) return;
    const int lane = threadIdx.x & 63;
    const int l = lane & 31;        // feature float4 group
    const int s = lane >> 5;        // 0..1 edge slot
    const int e0 = csr_off[v];
    const int e1 = csr_off[v + 1];
    float4 acc = make_float4(0.f, 0.f, 0.f, 0.f);
    int i = e0 + s;
    for (; i + 2 < e1; i += 4) {
        int sa = csr_se[i].x;      float wa = dinv[sa];
        int sb = csr_se[i + 2].x;  float wb = dinv[sb];
        float4 a = *(const float4*)&h[(size_t)sa * 128 + l * 4];
        float4 b = *(const float4*)&h[(size_t)sb * 128 + l * 4];
        acc.x = fmaf(a.x, wa, acc.x); acc.y = fmaf(a.y, wa, acc.y);
        acc.z = fmaf(a.z, wa, acc.z); acc.w = fmaf(a.w, wa, acc.w);
        acc.x = fmaf(b.x, wb, acc.x); acc.y = fmaf(b.y, wb, acc.y);
        acc.z = fmaf(b.z, wb, acc.z); acc.w = fmaf(b.w, wb, acc.w);
    }
    if (i < e1) {
        int sa = csr_se[i].x;
        float wa = dinv[sa];
        float4 a = *(const float4*)&h[(size_t)sa * 128 + l * 4];
        acc.x = fmaf(a.x, wa, acc.x); acc.y = fmaf(a.y, wa, acc.y);
        acc.z = fmaf(a.z, wa, acc.z); acc.w = fmaf(a.w, wa, acc.w);
    }
    acc.x += __shfl_xor(acc.x, 32);
    acc.y += __shfl_xor(acc.y, 32);
    acc.z += __shfl_xor(acc.z, 32);
    acc.w += __shfl_xor(acc.w, 32);
    if (s == 0) {
        float dv = dinv[v];
        float4 hv = *(const float4*)&h[(size_t)v * 128 + l * 4];
        float4 bb = *(const float4*)&bias[l * 4];
        float4 o;
        o.x = dv * (acc.x + hv.x * dv) + bb.x;
        o.y = dv * (acc.y + hv.y * dv) + bb.y;
        o.z = dv * (acc.z + hv.z * dv) + bb.z;
        o.w = dv * (acc.w + hv.w * dv) + bb.w;
        if (RELU) {
            o.x = fmaxf(o.x, 0.f); o.y = fmaxf(o.y, 0.f);
            o.z = fmaxf(o.z, 0.f); o.w = fmaxf(o.w, 0.f);
        }
        *(float4*)&out[(size_t)v * 128 + l * 4] = o;
    }
}

// 64-feat f32: 16 lanes x float4 = row, 4 slots; xor32+xor16 reduction.
__global__ __launch_bounds__(256) void k_agg64(const float* __restrict__ h,
                                               const int* __restrict__ csr_off,
                                               const int2* __restrict__ csr_se,
                                               const float* __restrict__ dinv,
                                               const float* __restrict__ bias,
                                               float* __restrict__ out, int N) {
    const int v = blockIdx.x * 4 + (threadIdx.x >> 6);
    if (v >= N) return;
    const int lane = threadIdx.x & 63;
    const int l = lane & 15;
    const int s = lane >> 4;        // 0..3
    const int e0 = csr_off[v];
    const int e1 = csr_off[v + 1];
    float4 acc = make_float4(0.f, 0.f, 0.f, 0.f);
    int i = e0 + s;
    for (; i + 4 < e1; i += 8) {
        int sa = csr_se[i].x;      float wa = dinv[sa];
        int sb = csr_se[i + 4].x;  float wb = dinv[sb];
        float4 a = *(const float4*)&h[(size_t)sa * 64 + l * 4];
        float4 b = *(const float4*)&h[(size_t)sb * 64 + l * 4];
        acc.x = fmaf(a.x, wa, acc.x); acc.y = fmaf(a.y, wa, acc.y);
        acc.z = fmaf(a.z, wa, acc.z); acc.w = fmaf(a.w, wa, acc.w);
        acc.x = fmaf(b.x, wb, acc.x); acc.y = fmaf(b.y, wb, acc.y);
        acc.z = fmaf(b.z, wb, acc.z); acc.w = fmaf(b.w, wb, acc.w);
    }
    if (i < e1) {
        int sa = csr_se[i].x;
        float wa = dinv[sa];
        float4 a = *(const float4*)&h[(size_t)sa * 64 + l * 4];
        acc.x = fmaf(a.x, wa, acc.x); acc.y = fmaf(a.y, wa, acc.y);
        acc.z = fmaf(a.z, wa, acc.z); acc.w = fmaf(a.w, wa, acc.w);
    }
    acc.x += __shfl_xor(acc.x, 32); acc.y += __shfl_xor(acc.y, 32);
    acc.z += __shfl_xor(acc.z, 32); acc.w += __shfl_xor(acc.w, 32);
    acc.x += __shfl_xor(acc.x, 16); acc.y += __shfl_xor(acc.y, 16);
    acc.z += __shfl_xor(acc.z, 16); acc.w += __shfl_xor(acc.w, 16);
    if (s == 0) {
        float dv = dinv[v];
        float4 hv = *(const float4*)&h[(size_t)v * 64 + l * 4];
        float4 bb = *(const float4*)&bias[l * 4];
        float4 o;
        o.x = dv * (acc.x + hv.x * dv) + bb.x;
        o.y = dv * (acc.y + hv.y * dv) + bb.y;
        o.z = dv * (acc.z + hv.z * dv) + bb.z;
        o.w = dv * (acc.w + hv.w * dv) + bb.w;
        *(float4*)&out[(size_t)v * 64 + l * 4] = o;
    }
}

// ----- bf16-gather aggregations (pass 2, post-mask), wave-per-node ---------
template <bool RELU>
__global__ __launch_bounds__(256) void k_agg128b(const unsigned short* __restrict__ h,
                                                 const int* __restrict__ csr_off,
                                                 const int2* __restrict__ csr_se,
                                                 const float* __restrict__ survive,
                                                 const float* __restrict__ dinv,
                                                 const float* __restrict__ bias,
                                                 unsigned short* __restrict__ out, int N) {
    const int v = blockIdx.x * 4 + (threadIdx.x >> 6);
    if (v >= N) return;
    const int lane = threadIdx.x & 63;
    const int l = lane & 15;        // 8-feature group
    const int s = lane >> 4;        // 0..3 edge slot
    const int e0 = csr_off[v];
    const int e1 = csr_off[v + 1];
    float acc[8];
#pragma unroll
    for (int j = 0; j < 8; j++) acc[j] = 0.f;
    int i = e0 + s;
    for (; i + 4 < e1; i += 8) {
        int sa = csr_se[i].x;
        int sb = csr_se[i + 4].x;
        float wa = dinv[sa] * survive[i];
        float wb = dinv[sb] * survive[i + 4];
        uint4 ua = *(const uint4*)&h[(size_t)sa * 128 + l * 8];
        uint4 ub = *(const uint4*)&h[(size_t)sb * 128 + l * 8];
        float f0, f1;
        unpack2(ua.x, f0, f1); acc[0] = fmaf(f0, wa, acc[0]); acc[1] = fmaf(f1, wa, acc[1]);
        unpack2(ua.y, f0, f1); acc[2] = fmaf(f0, wa, acc[2]); acc[3] = fmaf(f1, wa, acc[3]);
        unpack2(ua.z, f0, f1); acc[4] = fmaf(f0, wa, acc[4]); acc[5] = fmaf(f1, wa, acc[5]);
        unpack2(ua.w, f0, f1); acc[6] = fmaf(f0, wa, acc[6]); acc[7] = fmaf(f1, wa, acc[7]);
        unpack2(ub.x, f0, f1); acc[0] = fmaf(f0, wb, acc[0]); acc[1] = fmaf(f1, wb, acc[1]);
        unpack2(ub.y, f0, f1); acc[2] = fmaf(f0, wb, acc[2]); acc[3] = fmaf(f1, wb, acc[3]);
        unpack2(ub.z, f0, f1); acc[4] = fmaf(f0, wb, acc[4]); acc[5] = fmaf(f1, wb, acc[5]);
        unpack2(ub.w, f0, f1); acc[6] = fmaf(f0, wb, acc[6]); acc[7] = fmaf(f1, wb, acc[7]);
    }
    if (i < e1) {
        int sa = csr_se[i].x;
        float wa = dinv[sa] * survive[i];
        uint4 ua = *(const uint4*)&h[(size_t)sa * 128 + l * 8];
        float f0, f1;
        unpack2(ua.x, f0, f1); acc[0] = fmaf(f0, wa, acc[0]); acc[1] = fmaf(f1, wa, acc[1]);
        unpack2(ua.y, f0, f1); acc[2] = fmaf(f0, wa, acc[2]); acc[3] = fmaf(f1, wa, acc[3]);
        unpack2(ua.z, f0, f1); acc[4] = fmaf(f0, wa, acc[4]); acc[5] = fmaf(f1, wa, acc[5]);
        unpack2(ua.w, f0, f1); acc[6] = fmaf(f0, wa, acc[6]); acc[7] = fmaf(f1, wa, acc[7]);
    }
#pragma unroll
    for (int j = 0; j < 8; j++) acc[j] += __shfl_xor(acc[j], 32);
#pragma unroll
    for (int j = 0; j < 8; j++) acc[j] += __shfl_xor(acc[j], 16);
    if (s == 0) {
        float dv = dinv[v];
        uint4 uh = *(const uint4*)&h[(size_t)v * 128 + l * 8];
        float hv[8];
        unpack2(uh.x, hv[0], hv[1]); unpack2(uh.y, hv[2], hv[3]);
        unpack2(uh.z, hv[4], hv[5]); unpack2(uh.w, hv[6], hv[7]);
        unsigned u[4];
#pragma unroll
        for (int j2 = 0; j2 < 4; j2++) {
            float o0 = dv * (acc[2 * j2 + 0] + hv[2 * j2 + 0] * dv) + bias[l * 8 + 2 * j2 + 0];
            float o1 = dv * (acc[2 * j2 + 1] + hv[2 * j2 + 1] * dv) + bias[l * 8 + 2 * j2 + 1];
            if (RELU) { o0 = fmaxf(o0, 0.f); o1 = fmaxf(o1, 0.f); }
            u[j2] = bfpair(o0, o1);
        }
        *(uint4*)&out[(size_t)v * 128 + l * 8] = make_uint4(u[0], u[1], u[2], u[3]);
    }
}

// final layer: full edges, coef = dinvF[src], f32 out; 8 lanes x uint4, 8 slots.
__global__ __launch_bounds__(256) void k_agg64b(const unsigned short* __restrict__ h,
                                                const int* __restrict__ csr_off,
                                                const int2* __restrict__ csr_se,
                                                const float* __restrict__ dinv,
                                                const float* __restrict__ bias,
                                                float* __restrict__ out, int N) {
    const int v = blockIdx.x * 4 + (threadIdx.x >> 6);
    if (v >= N) return;
    const int lane = threadIdx.x & 63;
    const int l = lane & 7;         // 8-feature group
    const int s = lane >> 3;        // 0..7 edge slot
    const int e0 = csr_off[v];
    const int e1 = csr_off[v + 1];
    float acc[8];
#pragma unroll
    for (int j = 0; j < 8; j++) acc[j] = 0.f;
    for (int i = e0 + s; i < e1; i += 8) {
        int sa = csr_se[i].x;
        float wa = dinv[sa];
        uint4 ua = *(const uint4*)&h[(size_t)sa * 64 + l * 8];
        float f0, f1;
        unpack2(ua.x, f0, f1); acc[0] = fmaf(f0, wa, acc[0]); acc[1] = fmaf(f1, wa, acc[1]);
        unpack2(ua.y, f0, f1); acc[2] = fmaf(f0, wa, acc[2]); acc[3] = fmaf(f1, wa, acc[3]);
        unpack2(ua.z, f0, f1); acc[4] = fmaf(f0, wa, acc[4]); acc[5] = fmaf(f1, wa, acc[5]);
        unpack2(ua.w, f0, f1); acc[6] = fmaf(f0, wa, acc[6]); acc[7] = fmaf(f1, wa, acc[7]);
    }
#pragma unroll
    for (int j = 0; j < 8; j++) acc[j] += __shfl_xor(acc[j], 32);
#pragma unroll
    for (int j = 0; j < 8; j++) acc[j] += __shfl_xor(acc[j], 16);
#pragma unroll
    for (int j = 0; j < 8; j++) acc[j] += __shfl_xor(acc[j], 8);
    if (s == 0) {
        float dv = dinv[v];
        uint4 uh = *(const uint4*)&h[(size_t)v * 64 + l * 8];
        float hv[8];
        unpack2(uh.x, hv[0], hv[1]); unpack2(uh.y, hv[2], hv[3]);
        unpack2(uh.z, hv[4], hv[5]); unpack2(uh.w, hv[6], hv[7]);
        float o[8];
#pragma unroll
        for (int j = 0; j < 8; j++) o[j] = dv * (acc[j] + hv[j] * dv) + bias[l * 8 + j];
        *(float4*)&out[(size_t)v * 64 + l * 8 + 0] = make_float4(o[0], o[1], o[2], o[3]);
        *(float4*)&out[(size_t)v * 64 + l * 8 + 4] = make_float4(o[4], o[5], o[6], o[7]);
    }
}

extern "C" void kernel_launch(void* const* d_in, const int* in_sizes, int n_in,
                              void* d_out, int out_size, void* d_ws, size_t ws_size,
                              hipStream_t stream) {
    const float* x  = (const float*)d_in[0];
    const int*   ei = (const int*)d_in[1];
    const float* er = (const float*)d_in[2];
    const float* w0 = (const float*)d_in[3];
    const float* b0 = (const float*)d_in[4];
    const float* w1 = (const float*)d_in[5];
    const float* b1 = (const float*)d_in[6];
    const float* w2 = (const float*)d_in[7];
    const float* b2 = (const float*)d_in[8];
    const int N = in_sizes[0] / 128;
    const int E = in_sizes[2];
    const int* src  = ei;
    const int* dstv = ei + E;
    float* out = (float*)d_out;

    // workspace carve
    char* p = (char*)d_ws;
    auto alloc = [&](size_t bytes) {
        char* r = p;
        p += (bytes + 255) & ~(size_t)255;
        return r;
    };
    int* indeg     = (int*)alloc((size_t)N * 4);
    int* csr_off   = (int*)alloc((size_t)(N + 1) * 4);
    int* bsums     = (int*)alloc(1024);
    int* bcnt      = (int*)alloc((size_t)65536 * 4);
    int* sbase     = (int*)alloc((size_t)65537 * 4);
    int2* csr_se   = (int2*)alloc((size_t)E * 8);
    int2* stg      = (int2*)alloc((size_t)E * 8);   // staging; survive aliases
    float* dinvF   = (float*)alloc((size_t)N * 4);
    float* dinvM   = (float*)alloc((size_t)N * 4);
    float* hx      = (float*)alloc((size_t)N * 128 * 4);
    unsigned short* hxb = (unsigned short*)alloc((size_t)N * 128 * 2);
    float* wk1     = (float*)alloc((size_t)N * 128 * 4);
    float* wk2     = (float*)alloc((size_t)N * 128 * 4);
    float* tz      = (float*)alloc((size_t)N * 64 * 4);
    unsigned short* w0p3 = (unsigned short*)alloc((size_t)3 * 128 * 128 * 2);
    unsigned short* w1p3 = (unsigned short*)alloc((size_t)3 * 128 * 128 * 2);
    unsigned short* w2p3 = (unsigned short*)alloc((size_t)3 * 128 * 64 * 2);
    unsigned short* wk1b = (unsigned short*)wk1;
    unsigned short* wk2b = (unsigned short*)wk2;
    float* survive = (float*)stg;                 // stg dead after k_bfill

    const int nb = (N + 255) / 256;
    const int chunk = (E + 63) / 64;

    // weight packs (single launch)
    k_packw3_all<<<20, 256, 0, stream>>>(w0, w1, w2, w0p3, w1p3, w2p3);

    // ---- bucket-radix CSR build (no global atomics) ----
    k_bcount<<<64, 256, 0, stream>>>(dstv, bcnt, E, chunk);
    k_scan1<<<256, 256, 0, stream>>>(bcnt, sbase, bsums, 65536);
    k_scan2<<<1, 256, 0, stream>>>(bsums, 256);
    k_scan3<<<256, 256, 0, stream>>>(sbase, bsums, 65536, E);
    k_bscatter<<<64, 256, 0, stream>>>(src, dstv, er, sbase, stg, E, chunk);
    k_bindeg<<<1024, 256, 0, stream>>>(stg, sbase, indeg, dinvF, N);
    k_scan1<<<nb, 256, 0, stream>>>(indeg, csr_off, bsums, N);
    k_scan2<<<1, 256, 0, stream>>>(bsums, nb);
    k_scan3<<<nb, 256, 0, stream>>>(csr_off, bsums, N, E);
    k_bfill<<<1024, 256, 0, stream>>>(stg, sbase, csr_off, csr_se, N);

    const int gbm = (N + 63) / 64;
    const int ga = (N + 3) / 4;

    // shared first GEMM: f32 (pass1) + bf16 copy (pass2)
    k_gemm_split<128, true><<<gbm, 256, 0, stream>>>(x, w0p3, hx, hxb, N);

    // pass 1 (full graph, near-exact -> tz -> mask)
    k_agg128<true><<<ga, 256, 0, stream>>>(hx, csr_off, csr_se, dinvF, b0, wk1, N);
    k_gemm_split<128, false><<<gbm, 256, 0, stream>>>(wk1, w1p3, wk2, nullptr, N);
    k_agg128<true><<<ga, 256, 0, stream>>>(wk2, csr_off, csr_se, dinvF, b1, wk1, N);
    k_gemm_split<64, false><<<gbm, 256, 0, stream>>>(wk1, w2p3, wk2, nullptr, N);
    k_agg64<<<ga, 256, 0, stream>>>(wk2, csr_off, csr_se, dinvF, b2, tz, N);

    // edge sampling in CSR order (writes survive + dinvM), wave-per-node
    k_surv<<<ga, 256, 0, stream>>>(tz, csr_off, csr_se, survive, dinvM, N);

    // pass 2 (post-mask: bf16 gathers + bf16 MFMA GEMMs, plane-0 weights)
    k_agg128b<true><<<ga, 256, 0, stream>>>(hxb, csr_off, csr_se, survive, dinvM, b0, wk1b, N);
    k_gemm_mfma<128><<<gbm, 256, 0, stream>>>(wk1b, w1p3, wk2b, N);
    k_agg128b<true><<<ga, 256, 0, stream>>>(wk2b, csr_off, csr_se, survive, dinvM, b1, wk1b, N);
    k_gemm_mfma<64><<<gbm, 256, 0, stream>>>(wk1b, w2p3, wk2b, N);
    k_agg64b<<<ga, 256, 0, stream>>>(wk2b, csr_off, csr_se, dinvF, b2, out, N);
}

// Round 12
// 455.337 us; speedup vs baseline: 1.8055x; 1.0136x over previous
//
#include <hip/hip_runtime.h>

// ---------------------------------------------------------------------------
// GCN with edge sampling.  (R11 structure; scans fused, prolog fused.)
//  Pass 1 (-> tz -> mask) uses split-bf16 MFMA GEMMs (3-plane Ozaki split,
//  6 cross terms, error ~2^-26) + exact f32 aggs -> mask bit-stable.
//  Pass 2 (post-mask) is bf16 end-to-end.
//  CSR build: bucket-radix (bucket = dst>>6), LDS atomics only.
//  Aggregations: wave-per-node, no LDS, no barriers (shfl_xor reduction).
//  agg128 f32 @ ~59us = gather-fabric floor (3 structural variants, traffic
//  matches unique-footprint model 0.88*8*25.6MB).
// conv: out[v] = dinv[v]*(sum_e h[src]*dinv[src]*m[e] + h[v]*dinv[v]) + b
// ---------------------------------------------------------------------------

typedef __attribute__((ext_vector_type(8))) short bf16x8;
typedef __attribute__((ext_vector_type(4))) float f32x4;

__device__ inline unsigned bfpair(float lo, float hi) {   // pack 2 f32 -> bf16x2 RNE
    unsigned a = __float_as_uint(lo), b = __float_as_uint(hi);
    a = (a + 0x7FFFu + ((a >> 16) & 1u)) >> 16;
    b = (b + 0x7FFFu + ((b >> 16) & 1u)) & 0xFFFF0000u;
    return a | b;
}
__device__ inline unsigned short bf1(float v) {
    unsigned u = __float_as_uint(v);
    return (unsigned short)((u + 0x7FFFu + ((u >> 16) & 1u)) >> 16);
}
__device__ inline void unpack2(unsigned u, float& f0, float& f1) {
    f0 = __uint_as_float(u << 16);
    f1 = __uint_as_float(u & 0xFFFF0000u);
}

// ---------------- scans ----------------
__global__ void k_scan1(const int* __restrict__ in, int* __restrict__ out,
                        int* __restrict__ bsums, int N) {
    __shared__ int tmp[256];
    int i = blockIdx.x * 256 + threadIdx.x;
    int v = (i < N) ? in[i] : 0;
    tmp[threadIdx.x] = v;
    __syncthreads();
    for (int off = 1; off < 256; off <<= 1) {
        int t = (threadIdx.x >= off) ? tmp[threadIdx.x - off] : 0;
        __syncthreads();
        tmp[threadIdx.x] += t;
        __syncthreads();
    }
    if (i < N) out[i] = tmp[threadIdx.x] - v;   // exclusive (within block)
    if (threadIdx.x == 255) bsums[blockIdx.x] = tmp[255];
}

// scan2 folded in: every block redundantly scans bsums (nb<=256) in LDS,
// adds its own exclusive prefix.
__global__ void k_scan3(int* __restrict__ out, const int* __restrict__ bsums,
                        int nb, int N, int E) {
    __shared__ int tmp[256];
    int t = threadIdx.x;
    int v = (t < nb) ? bsums[t] : 0;
    tmp[t] = v;
    __syncthreads();
    for (int off = 1; off < 256; off <<= 1) {
        int u = (t >= off) ? tmp[t - off] : 0;
        __syncthreads();
        tmp[t] += u;
        __syncthreads();
    }
    int bv = (blockIdx.x < nb) ? bsums[blockIdx.x] : 0;
    int prefix = tmp[blockIdx.x] - bv;   // exclusive prefix for this block
    int i = blockIdx.x * 256 + t;
    if (i < N) out[i] += prefix;
    if (i == 0) out[N] = E;
}

// pack W -> 3 bf16 split planes (plane 0 = bf16(W), reused by pass-2 GEMMs)
__device__ inline void packw3_one(const float* __restrict__ W, unsigned short* __restrict__ Wp,
                                  int OUTC, int idx) {
    int l = idx & 63;
    int tk = idx >> 6;
    int kb = tk & 3;
    int ct = tk >> 2;
    size_t PL = (size_t)(OUTC / 16) * 4 * 64 * 8;
    unsigned short v0[8], v1[8], v2[8];
#pragma unroll
    for (int i = 0; i < 8; i++) {
        float wv = W[(kb * 32 + ((l >> 4) * 8) + i) * OUTC + ct * 16 + (l & 15)];
        unsigned short h0 = bf1(wv);
        float f0 = __uint_as_float((unsigned)h0 << 16);
        float r1 = wv - f0;
        unsigned short h1 = bf1(r1);
        float f1 = __uint_as_float((unsigned)h1 << 16);
        unsigned short h2 = bf1(r1 - f1);
        v0[i] = h0; v1[i] = h1; v2[i] = h2;
    }
    auto st = [](unsigned short* dst, unsigned short* v) {
        uint4 u;
        u.x = v[0] | ((unsigned)v[1] << 16);
        u.y = v[2] | ((unsigned)v[3] << 16);
        u.z = v[4] | ((unsigned)v[5] << 16);
        u.w = v[6] | ((unsigned)v[7] << 16);
        *(uint4*)dst = u;
    };
    st(&Wp[(size_t)idx * 8], v0);
    st(&Wp[PL + (size_t)idx * 8], v1);
    st(&Wp[2 * PL + (size_t)idx * 8], v2);
}

// prolog: blocks 0..19 = weight packs; blocks 20..83 = bucket count (fused).
__global__ __launch_bounds__(256) void k_prolog(const float* __restrict__ w0,
                                                const float* __restrict__ w1,
                                                const float* __restrict__ w2,
                                                unsigned short* __restrict__ w0p,
                                                unsigned short* __restrict__ w1p,
                                                unsigned short* __restrict__ w2p,
                                                const int* __restrict__ dst,
                                                int* __restrict__ cnt, int E, int chunk) {
    int b = blockIdx.x;
    if (b < 8) { packw3_one(w0, w0p, 128, b * 256 + threadIdx.x); return; }
    if (b < 16) { packw3_one(w1, w1p, 128, (b - 8) * 256 + threadIdx.x); return; }
    if (b < 20) { packw3_one(w2, w2p, 64, (b - 16) * 256 + threadIdx.x); return; }
    // bucket count, chunk index = b - 20
    __shared__ int h[1024];
    for (int i = threadIdx.x; i < 1024; i += 256) h[i] = 0;
    __syncthreads();
    int cb = b - 20;
    int beg = cb * chunk, end = min(E, beg + chunk);
    for (int e = beg + threadIdx.x; e < end; e += 256)
        atomicAdd(&h[dst[e] >> 6], 1);
    __syncthreads();
    for (int bb = threadIdx.x; bb < 1024; bb += 256)
        cnt[bb * 64 + cb] = h[bb];
}

// staging payload: .x = src | (dst&63)<<16  (src < 65536), .y = er bits
__global__ __launch_bounds__(256) void k_bscatter(const int* __restrict__ src,
                                                  const int* __restrict__ dst,
                                                  const float* __restrict__ er,
                                                  const int* __restrict__ sbase,
                                                  int2* __restrict__ stg, int E, int chunk) {
    __shared__ int cur[1024];
    for (int i = threadIdx.x; i < 1024; i += 256) cur[i] = 0;
    __syncthreads();
    int beg = blockIdx.x * chunk, end = min(E, beg + chunk);
    for (int e = beg + threadIdx.x; e < end; e += 256) {
        int d = dst[e];
        int b = d >> 6;
        int loc = atomicAdd(&cur[b], 1);
        int pos = sbase[b * 64 + blockIdx.x] + loc;
        stg[pos] = make_int2(src[e] | ((d & 63) << 16), (int)__float_as_uint(er[e]));
    }
}

// per-bucket indeg + dinvF
__global__ __launch_bounds__(256) void k_bindeg(const int2* __restrict__ stg,
                                                const int* __restrict__ sbase,
                                                int* __restrict__ indeg,
                                                float* __restrict__ dinvF, int N) {
    __shared__ int cnt[64];
    if (threadIdx.x < 64) cnt[threadIdx.x] = 0;
    __syncthreads();
    int b = blockIdx.x;
    int beg = sbase[b * 64], end = sbase[(b + 1) * 64];
    for (int i = beg + threadIdx.x; i < end; i += 256)
        atomicAdd(&cnt[(stg[i].x >> 16) & 63], 1);
    __syncthreads();
    if (threadIdx.x < 64) {
        int node = b * 64 + threadIdx.x;
        if (node < N) {
            int c = cnt[threadIdx.x];
            indeg[node] = c;
            dinvF[node] = 1.0f / sqrtf((float)c + 1.0f);
        }
    }
}

// bucket owns its 64 dst nodes exclusively -> LDS cursors give unique slots.
__global__ __launch_bounds__(256) void k_bfill(const int2* __restrict__ stg,
                                               const int* __restrict__ sbase,
                                               const int* __restrict__ csr_off,
                                               int2* __restrict__ csr_se, int N) {
    __shared__ int cur[64];
    int b = blockIdx.x;
    if (threadIdx.x < 64) {
        int node = b * 64 + threadIdx.x;
        cur[threadIdx.x] = (node < N) ? csr_off[node] : 0;
    }
    __syncthreads();
    int beg = sbase[b * 64], end = sbase[(b + 1) * 64];
    for (int i = beg + threadIdx.x; i < end; i += 256) {
        int2 se = stg[i];
        int j = (se.x >> 16) & 63;
        int pos = atomicAdd(&cur[j], 1);
        csr_se[pos] = make_int2(se.x & 0xFFFF, se.y);
    }
}

// mask in CSR order: wave-per-node (4 nodes/block), 4 slots x 16 lanes.
__global__ __launch_bounds__(256) void k_surv(const float* __restrict__ tz,
                                              const int* __restrict__ csr_off,
                                              const int2* __restrict__ csr_se,
                                              float* __restrict__ survive,
                                              float* __restrict__ dinvM, int N) {
    const int v = blockIdx.x * 4 + (threadIdx.x >> 6);
    if (v >= N) return;
    const int lane = threadIdx.x & 63;
    const int l = lane & 15;
    const int s = lane >> 4;        // 0..3 edge slot
    const int e0 = csr_off[v];
    const int e1 = csr_off[v + 1];
    const float4 tv = *(const float4*)&tz[(size_t)v * 64 + l * 4];
    int cnt = 0;
    for (int i = e0 + s; i < e1; i += 4) {
        int2 se = csr_se[i];
        const float4 a = *(const float4*)&tz[(size_t)se.x * 64 + l * 4];
        float p = a.x * tv.x + a.y * tv.y + a.z * tv.z + a.w * tv.w;
        p += __shfl_xor(p, 1, 16);
        p += __shfl_xor(p, 2, 16);
        p += __shfl_xor(p, 4, 16);
        p += __shfl_xor(p, 8, 16);
        float sg = 1.0f / (1.0f + expf(-p));
        float m = (sg > __uint_as_float((unsigned)se.y)) ? 1.0f : 0.0f;
        if (l == 0) {
            survive[i] = m;
            cnt += (m != 0.0f) ? 1 : 0;
        }
    }
    cnt += __shfl_xor(cnt, 16);
    cnt += __shfl_xor(cnt, 32);
    if (lane == 0) dinvM[v] = 1.0f / sqrtf((float)cnt + 1.0f);
}

// split-bf16 MFMA GEMM (pass 1): 6 cross terms (00,10,20 | 01,11,02),
// error ~2^-26. f32 out (+ optional bf16 copy).
template <int OUTC, bool WB16>
__global__ __launch_bounds__(256) void k_gemm_split(const float* __restrict__ A,
                                                    const unsigned short* __restrict__ Wp,
                                                    float* __restrict__ Cout,
                                                    unsigned short* __restrict__ Cb, int N) {
    constexpr int CT = OUTC / 16;
    constexpr int PL = CT * 4 * 64 * 8;
    constexpr int LDW = OUTC + 4;
    __shared__ float eps[64 * LDW];
    const int w = threadIdx.x >> 6;
    const int l = threadIdx.x & 63;
    int row = blockIdx.x * 64 + w * 16 + (l & 15);
    int rowc = (row < N) ? row : (N - 1);

    bf16x8 a0[4], a1[4], a2[4];
#pragma unroll
    for (int kb = 0; kb < 4; kb++) {
        const float* pa = &A[(size_t)rowc * 128 + kb * 32 + ((l >> 4) * 8)];
        float4 x0 = *(const float4*)pa;
        float4 x1 = *(const float4*)(pa + 4);
        float xa[8] = {x0.x, x0.y, x0.z, x0.w, x1.x, x1.y, x1.z, x1.w};
#pragma unroll
        for (int i = 0; i < 8; i++) {
            unsigned short h0 = bf1(xa[i]);
            float f0 = __uint_as_float((unsigned)h0 << 16);
            float r1 = xa[i] - f0;
            unsigned short h1 = bf1(r1);
            float f1 = __uint_as_float((unsigned)h1 << 16);
            unsigned short h2 = bf1(r1 - f1);
            a0[kb][i] = (short)h0;
            a1[kb][i] = (short)h1;
            a2[kb][i] = (short)h2;
        }
    }
#pragma unroll
    for (int ct = 0; ct < CT; ct++) {
        f32x4 accA = {0.f, 0.f, 0.f, 0.f};
        f32x4 accB = {0.f, 0.f, 0.f, 0.f};
#pragma unroll
        for (int kb = 0; kb < 4; kb++) {
            const size_t bo = ((size_t)(ct * 4 + kb) * 64 + l) * 8;
            bf16x8 b0 = *(const bf16x8*)&Wp[bo];
            bf16x8 b1 = *(const bf16x8*)&Wp[PL + bo];
            bf16x8 b2 = *(const bf16x8*)&Wp[2 * PL + bo];
            accA = __builtin_amdgcn_mfma_f32_16x16x32_bf16(a0[kb], b0, accA, 0, 0, 0);
            accB = __builtin_amdgcn_mfma_f32_16x16x32_bf16(a0[kb], b1, accB, 0, 0, 0);
            accA = __builtin_amdgcn_mfma_f32_16x16x32_bf16(a1[kb], b0, accA, 0, 0, 0);
            accB = __builtin_amdgcn_mfma_f32_16x16x32_bf16(a1[kb], b1, accB, 0, 0, 0);
            accA = __builtin_amdgcn_mfma_f32_16x16x32_bf16(a2[kb], b0, accA, 0, 0, 0);
            accB = __builtin_amdgcn_mfma_f32_16x16x32_bf16(a0[kb], b2, accB, 0, 0, 0);
        }
        // C/D map: col = lane&15, row = (lane>>4)*4 + r  [HW-verified]
#pragma unroll
        for (int r = 0; r < 4; r++) {
            int rr = w * 16 + (l >> 4) * 4 + r;
            eps[rr * LDW + ct * 16 + (l & 15)] = accA[r] + accB[r];
        }
    }
    __syncthreads();
    constexpr int NF4 = 64 * OUTC / 4;
    for (int idx = threadIdx.x; idx < NF4; idx += 256) {
        int rl = idx / (OUTC / 4);
        int cg = idx % (OUTC / 4);
        int grow = blockIdx.x * 64 + rl;
        if (grow < N) {
            const float* sp = &eps[rl * LDW + cg * 4];
            float4 vv = make_float4(sp[0], sp[1], sp[2], sp[3]);
            *(float4*)&Cout[(size_t)grow * OUTC + cg * 4] = vv;
            if (WB16)
                *(uint2*)&Cb[(size_t)grow * OUTC + cg * 4] =
                    make_uint2(bfpair(vv.x, vv.y), bfpair(vv.z, vv.w));
        }
    }
}

// plain bf16 MFMA GEMM (pass 2): A bf16, Wpk = plane 0 of packw3, bf16 out.
template <int OUTC>
__global__ __launch_bounds__(256) void k_gemm_mfma(const unsigned short* __restrict__ A,
                                                   const unsigned short* __restrict__ Wpk,
                                                   unsigned short* __restrict__ C, int N) {
    constexpr int CT = OUTC / 16;
    __shared__ unsigned short eps[64 * OUTC];
    const int w = threadIdx.x >> 6;
    const int l = threadIdx.x & 63;
    const int rowl = (w * 16) + (l & 15);
    int row = blockIdx.x * 64 + rowl;
    int rowc = (row < N) ? row : (N - 1);

    bf16x8 a[4];
#pragma unroll
    for (int kb = 0; kb < 4; kb++)
        a[kb] = *(const bf16x8*)&A[(size_t)rowc * 128 + kb * 32 + ((l >> 4) * 8)];

#pragma unroll
    for (int ct = 0; ct < CT; ct++) {
        f32x4 acc = {0.f, 0.f, 0.f, 0.f};
#pragma unroll
        for (int kb = 0; kb < 4; kb++) {
            bf16x8 b = *(const bf16x8*)&Wpk[((size_t)(ct * 4 + kb) * 64 + l) * 8];
            acc = __builtin_amdgcn_mfma_f32_16x16x32_bf16(a[kb], b, acc, 0, 0, 0);
        }
#pragma unroll
        for (int r = 0; r < 4; r++) {
            int rr = w * 16 + (l >> 4) * 4 + r;
            eps[rr * OUTC + ct * 16 + (l & 15)] = bf1(acc[r]);
        }
    }
    __syncthreads();
    constexpr int NU4 = 64 * OUTC / 8;
    for (int idx = threadIdx.x; idx < NU4; idx += 256) {
        int rl = idx / (OUTC / 8);
        int cg = idx % (OUTC / 8);
        int grow = blockIdx.x * 64 + rl;
        if (grow < N)
            *(uint4*)&C[(size_t)grow * OUTC + cg * 8] = *(const uint4*)&eps[rl * OUTC + cg * 8];
    }
}

// -------- fp32 aggregations (pass 1, mask-critical), wave-per-node ---------
template <bool RELU>
__global__ __launch_bounds__(256) void k_agg128(const float* __restrict__ h,
                                                const int* __restrict__ csr_off,
                                                const int2* __restrict__ csr_se,
                                                const float* __restrict__ dinv,
                                                const float* __restrict__ bias,
                                                float* __restrict__ out, int N) {
    const int v = blockIdx.x * 4 + (threadIdx.x >> 6);
    if (v >= N) return;
    const int lane = threadIdx.x & 63;
    const int l = lane & 31;        // feature float4 group
    const int s = lane >> 5;        // 0..1 edge slot
    const int e0 = csr_off[v];
    const int e1 = csr_off[v + 1];
    float4 acc = make_float4(0.f, 0.f, 0.f, 0.f);
    int i = e0 + s;
    for (; i + 2 < e1; i += 4) {
        int sa = csr_se[i].x;      float wa = dinv[sa];
        int sb = csr_se[i + 2].x;  float wb = dinv[sb];
        float4 a = *(const float4*)&h[(size_t)sa * 128 + l * 4];
        float4 b = *(const float4*)&h[(size_t)sb * 128 + l * 4];
        acc.x = fmaf(a.x, wa, acc.x); acc.y = fmaf(a.y, wa, acc.y);
        acc.z = fmaf(a.z, wa, acc.z); acc.w = fmaf(a.w, wa, acc.w);
        acc.x = fmaf(b.x, wb, acc.x); acc.y = fmaf(b.y, wb, acc.y);
        acc.z = fmaf(b.z, wb, acc.z); acc.w = fmaf(b.w, wb, acc.w);
    }
    if (i < e1) {
        int sa = csr_se[i].x;
        float wa = dinv[sa];
        float4 a = *(const float4*)&h[(size_t)sa * 128 + l * 4];
        acc.x = fmaf(a.x, wa, acc.x); acc.y = fmaf(a.y, wa, acc.y);
        acc.z = fmaf(a.z, wa, acc.z); acc.w = fmaf(a.w, wa, acc.w);
    }
    acc.x += __shfl_xor(acc.x, 32);
    acc.y += __shfl_xor(acc.y, 32);
    acc.z += __shfl_xor(acc.z, 32);
    acc.w += __shfl_xor(acc.w, 32);
    if (s == 0) {
        float dv = dinv[v];
        float4 hv = *(const float4*)&h[(size_t)v * 128 + l * 4];
        float4 bb = *(const float4*)&bias[l * 4];
        float4 o;
        o.x = dv * (acc.x + hv.x * dv) + bb.x;
        o.y = dv * (acc.y + hv.y * dv) + bb.y;
        o.z = dv * (acc.z + hv.z * dv) + bb.z;
        o.w = dv * (acc.w + hv.w * dv) + bb.w;
        if (RELU) {
            o.x = fmaxf(o.x, 0.f); o.y = fmaxf(o.y, 0.f);
            o.z = fmaxf(o.z, 0.f); o.w = fmaxf(o.w, 0.f);
        }
        *(float4*)&out[(size_t)v * 128 + l * 4] = o;
    }
}

// 64-feat f32: 16 lanes x float4 = row, 4 slots; xor32+xor16 reduction.
__global__ __launch_bounds__(256) void k_agg64(const float* __restrict__ h,
                                               const int* __restrict__ csr_off,
                                               const int2* __restrict__ csr_se,
                                               const float* __restrict__ dinv,
                                               const float* __restrict__ bias,
                                               float* __restrict__ out, int N) {
    const int v = blockIdx.x * 4 + (threadIdx.x >> 6);
    if (v >= N) return;
    const int lane = threadIdx.x & 63;
    const int l = lane & 15;
    const int s = lane >> 4;        // 0..3
    const int e0 = csr_off[v];
    const int e1 = csr_off[v + 1];
    float4 acc = make_float4(0.f, 0.f, 0.f, 0.f);
    int i = e0 + s;
    for (; i + 4 < e1; i += 8) {
        int sa = csr_se[i].x;      float wa = dinv[sa];
        int sb = csr_se[i + 4].x;  float wb = dinv[sb];
        float4 a = *(const float4*)&h[(size_t)sa * 64 + l * 4];
        float4 b = *(const float4*)&h[(size_t)sb * 64 + l * 4];
        acc.x = fmaf(a.x, wa, acc.x); acc.y = fmaf(a.y, wa, acc.y);
        acc.z = fmaf(a.z, wa, acc.z); acc.w = fmaf(a.w, wa, acc.w);
        acc.x = fmaf(b.x, wb, acc.x); acc.y = fmaf(b.y, wb, acc.y);
        acc.z = fmaf(b.z, wb, acc.z); acc.w = fmaf(b.w, wb, acc.w);
    }
    if (i < e1) {
        int sa = csr_se[i].x;
        float wa = dinv[sa];
        float4 a = *(const float4*)&h[(size_t)sa * 64 + l * 4];
        acc.x = fmaf(a.x, wa, acc.x); acc.y = fmaf(a.y, wa, acc.y);
        acc.z = fmaf(a.z, wa, acc.z); acc.w = fmaf(a.w, wa, acc.w);
    }
    acc.x += __shfl_xor(acc.x, 32); acc.y += __shfl_xor(acc.y, 32);
    acc.z += __shfl_xor(acc.z, 32); acc.w += __shfl_xor(acc.w, 32);
    acc.x += __shfl_xor(acc.x, 16); acc.y += __shfl_xor(acc.y, 16);
    acc.z += __shfl_xor(acc.z, 16); acc.w += __shfl_xor(acc.w, 16);
    if (s == 0) {
        float dv = dinv[v];
        float4 hv = *(const float4*)&h[(size_t)v * 64 + l * 4];
        float4 bb = *(const float4*)&bias[l * 4];
        float4 o;
        o.x = dv * (acc.x + hv.x * dv) + bb.x;
        o.y = dv * (acc.y + hv.y * dv) + bb.y;
        o.z = dv * (acc.z + hv.z * dv) + bb.z;
        o.w = dv * (acc.w + hv.w * dv) + bb.w;
        *(float4*)&out[(size_t)v * 64 + l * 4] = o;
    }
}

// ----- bf16-gather aggregations (pass 2, post-mask), wave-per-node ---------
template <bool RELU>
__global__ __launch_bounds__(256) void k_agg128b(const unsigned short* __restrict__ h,
                                                 const int* __restrict__ csr_off,
                                                 const int2* __restrict__ csr_se,
                                                 const float* __restrict__ survive,
                                                 const float* __restrict__ dinv,
                                                 const float* __restrict__ bias,
                                                 unsigned short* __restrict__ out, int N) {
    const int v = blockIdx.x * 4 + (threadIdx.x >> 6);
    if (v >= N) return;
    const int lane = threadIdx.x & 63;
    const int l = lane & 15;        // 8-feature group
    const int s = lane >> 4;        // 0..3 edge slot
    const int e0 = csr_off[v];
    const int e1 = csr_off[v + 1];
    float acc[8];
#pragma unroll
    for (int j = 0; j < 8; j++) acc[j] = 0.f;
    int i = e0 + s;
    for (; i + 4 < e1; i += 8) {
        int sa = csr_se[i].x;
        int sb = csr_se[i + 4].x;
        float wa = dinv[sa] * survive[i];
        float wb = dinv[sb] * survive[i + 4];
        uint4 ua = *(const uint4*)&h[(size_t)sa * 128 + l * 8];
        uint4 ub = *(const uint4*)&h[(size_t)sb * 128 + l * 8];
        float f0, f1;
        unpack2(ua.x, f0, f1); acc[0] = fmaf(f0, wa, acc[0]); acc[1] = fmaf(f1, wa, acc[1]);
        unpack2(ua.y, f0, f1); acc[2] = fmaf(f0, wa, acc[2]); acc[3] = fmaf(f1, wa, acc[3]);
        unpack2(ua.z, f0, f1); acc[4] = fmaf(f0, wa, acc[4]); acc[5] = fmaf(f1, wa, acc[5]);
        unpack2(ua.w, f0, f1); acc[6] = fmaf(f0, wa, acc[6]); acc[7] = fmaf(f1, wa, acc[7]);
        unpack2(ub.x, f0, f1); acc[0] = fmaf(f0, wb, acc[0]); acc[1] = fmaf(f1, wb, acc[1]);
        unpack2(ub.y, f0, f1); acc[2] = fmaf(f0, wb, acc[2]); acc[3] = fmaf(f1, wb, acc[3]);
        unpack2(ub.z, f0, f1); acc[4] = fmaf(f0, wb, acc[4]); acc[5] = fmaf(f1, wb, acc[5]);
        unpack2(ub.w, f0, f1); acc[6] = fmaf(f0, wb, acc[6]); acc[7] = fmaf(f1, wb, acc[7]);
    }
    if (i < e1) {
        int sa = csr_se[i].x;
        float wa = dinv[sa] * survive[i];
        uint4 ua = *(const uint4*)&h[(size_t)sa * 128 + l * 8];
        float f0, f1;
        unpack2(ua.x, f0, f1); acc[0] = fmaf(f0, wa, acc[0]); acc[1] = fmaf(f1, wa, acc[1]);
        unpack2(ua.y, f0, f1); acc[2] = fmaf(f0, wa, acc[2]); acc[3] = fmaf(f1, wa, acc[3]);
        unpack2(ua.z, f0, f1); acc[4] = fmaf(f0, wa, acc[4]); acc[5] = fmaf(f1, wa, acc[5]);
        unpack2(ua.w, f0, f1); acc[6] = fmaf(f0, wa, acc[6]); acc[7] = fmaf(f1, wa, acc[7]);
    }
#pragma unroll
    for (int j = 0; j < 8; j++) acc[j] += __shfl_xor(acc[j], 32);
#pragma unroll
    for (int j = 0; j < 8; j++) acc[j] += __shfl_xor(acc[j], 16);
    if (s == 0) {
        float dv = dinv[v];
        uint4 uh = *(const uint4*)&h[(size_t)v * 128 + l * 8];
        float hv[8];
        unpack2(uh.x, hv[0], hv[1]); unpack2(uh.y, hv[2], hv[3]);
        unpack2(uh.z, hv[4], hv[5]); unpack2(uh.w, hv[6], hv[7]);
        unsigned u[4];
#pragma unroll
        for (int j2 = 0; j2 < 4; j2++) {
            float o0 = dv * (acc[2 * j2 + 0] + hv[2 * j2 + 0] * dv) + bias[l * 8 + 2 * j2 + 0];
            float o1 = dv * (acc[2 * j2 + 1] + hv[2 * j2 + 1] * dv) + bias[l * 8 + 2 * j2 + 1];
            if (RELU) { o0 = fmaxf(o0, 0.f); o1 = fmaxf(o1, 0.f); }
            u[j2] = bfpair(o0, o1);
        }
        *(uint4*)&out[(size_t)v * 128 + l * 8] = make_uint4(u[0], u[1], u[2], u[3]);
    }
}

// final layer: full edges, coef = dinvF[src], f32 out; 8 lanes x uint4, 8 slots.
__global__ __launch_bounds__(256) void k_agg64b(const unsigned short* __restrict__ h,
                                                const int* __restrict__ csr_off,
                                                const int2* __restrict__ csr_se,
                                                const float* __restrict__ dinv,
                                                const float* __restrict__ bias,
                                                float* __restrict__ out, int N) {
    const int v = blockIdx.x * 4 + (threadIdx.x >> 6);
    if (v >= N) return;
    const int lane = threadIdx.x & 63;
    const int l = lane & 7;         // 8-feature group
    const int s = lane >> 3;        // 0..7 edge slot
    const int e0 = csr_off[v];
    const int e1 = csr_off[v + 1];
    float acc[8];
#pragma unroll
    for (int j = 0; j < 8; j++) acc[j] = 0.f;
    for (int i = e0 + s; i < e1; i += 8) {
        int sa = csr_se[i].x;
        float wa = dinv[sa];
        uint4 ua = *(const uint4*)&h[(size_t)sa * 64 + l * 8];
        float f0, f1;
        unpack2(ua.x, f0, f1); acc[0] = fmaf(f0, wa, acc[0]); acc[1] = fmaf(f1, wa, acc[1]);
        unpack2(ua.y, f0, f1); acc[2] = fmaf(f0, wa, acc[2]); acc[3] = fmaf(f1, wa, acc[3]);
        unpack2(ua.z, f0, f1); acc[4] = fmaf(f0, wa, acc[4]); acc[5] = fmaf(f1, wa, acc[5]);
        unpack2(ua.w, f0, f1); acc[6] = fmaf(f0, wa, acc[6]); acc[7] = fmaf(f1, wa, acc[7]);
    }
#pragma unroll
    for (int j = 0; j < 8; j++) acc[j] += __shfl_xor(acc[j], 32);
#pragma unroll
    for (int j = 0; j < 8; j++) acc[j] += __shfl_xor(acc[j], 16);
#pragma unroll
    for (int j = 0; j < 8; j++) acc[j] += __shfl_xor(acc[j], 8);
    if (s == 0) {
        float dv = dinv[v];
        uint4 uh = *(const uint4*)&h[(size_t)v * 64 + l * 8];
        float hv[8];
        unpack2(uh.x, hv[0], hv[1]); unpack2(uh.y, hv[2], hv[3]);
        unpack2(uh.z, hv[4], hv[5]); unpack2(uh.w, hv[6], hv[7]);
        float o[8];
#pragma unroll
        for (int j = 0; j < 8; j++) o[j] = dv * (acc[j] + hv[j] * dv) + bias[l * 8 + j];
        *(float4*)&out[(size_t)v * 64 + l * 8 + 0] = make_float4(o[0], o[1], o[2], o[3]);
        *(float4*)&out[(size_t)v * 64 + l * 8 + 4] = make_float4(o[4], o[5], o[6], o[7]);
    }
}

extern "C" void kernel_launch(void* const* d_in, const int* in_sizes, int n_in,
                              void* d_out, int out_size, void* d_ws, size_t ws_size,
                              hipStream_t stream) {
    const float* x  = (const float*)d_in[0];
    const int*   ei = (const int*)d_in[1];
    const float* er = (const float*)d_in[2];
    const float* w0 = (const float*)d_in[3];
    const float* b0 = (const float*)d_in[4];
    const float* w1 = (const float*)d_in[5];
    const float* b1 = (const float*)d_in[6];
    const float* w2 = (const float*)d_in[7];
    const float* b2 = (const float*)d_in[8];
    const int N = in_sizes[0] / 128;
    const int E = in_sizes[2];
    const int* src  = ei;
    const int* dstv = ei + E;
    float* out = (float*)d_out;

    // workspace carve
    char* p = (char*)d_ws;
    auto alloc = [&](size_t bytes) {
        char* r = p;
        p += (bytes + 255) & ~(size_t)255;
        return r;
    };
    int* indeg     = (int*)alloc((size_t)N * 4);
    int* csr_off   = (int*)alloc((size_t)(N + 1) * 4);
    int* bsums     = (int*)alloc(1024);
    int* bcnt      = (int*)alloc((size_t)65536 * 4);
    int* sbase     = (int*)alloc((size_t)65537 * 4);
    int2* csr_se   = (int2*)alloc((size_t)E * 8);
    int2* stg      = (int2*)alloc((size_t)E * 8);   // staging; survive aliases
    float* dinvF   = (float*)alloc((size_t)N * 4);
    float* dinvM   = (float*)alloc((size_t)N * 4);
    float* hx      = (float*)alloc((size_t)N * 128 * 4);
    unsigned short* hxb = (unsigned short*)alloc((size_t)N * 128 * 2);
    float* wk1     = (float*)alloc((size_t)N * 128 * 4);
    float* wk2     = (float*)alloc((size_t)N * 128 * 4);
    float* tz      = (float*)alloc((size_t)N * 64 * 4);
    unsigned short* w0p3 = (unsigned short*)alloc((size_t)3 * 128 * 128 * 2);
    unsigned short* w1p3 = (unsigned short*)alloc((size_t)3 * 128 * 128 * 2);
    unsigned short* w2p3 = (unsigned short*)alloc((size_t)3 * 128 * 64 * 2);
    unsigned short* wk1b = (unsigned short*)wk1;
    unsigned short* wk2b = (unsigned short*)wk2;
    float* survive = (float*)stg;                 // stg dead after k_bfill

    const int nb = (N + 255) / 256;
    const int chunk = (E + 63) / 64;

    // prolog: weight packs (blocks 0..19) + bucket count (blocks 20..83)
    k_prolog<<<84, 256, 0, stream>>>(w0, w1, w2, w0p3, w1p3, w2p3, dstv, bcnt, E, chunk);

    // ---- bucket-radix CSR build (no global atomics) ----
    k_scan1<<<256, 256, 0, stream>>>(bcnt, sbase, bsums, 65536);
    k_scan3<<<256, 256, 0, stream>>>(sbase, bsums, 256, 65536, E);
    k_bscatter<<<64, 256, 0, stream>>>(src, dstv, er, sbase, stg, E, chunk);
    k_bindeg<<<1024, 256, 0, stream>>>(stg, sbase, indeg, dinvF, N);
    k_scan1<<<nb, 256, 0, stream>>>(indeg, csr_off, bsums, N);
    k_scan3<<<nb, 256, 0, stream>>>(csr_off, bsums, nb, N, E);
    k_bfill<<<1024, 256, 0, stream>>>(stg, sbase, csr_off, csr_se, N);

    const int gbm = (N + 63) / 64;
    const int ga = (N + 3) / 4;

    // shared first GEMM: f32 (pass1) + bf16 copy (pass2)
    k_gemm_split<128, true><<<gbm, 256, 0, stream>>>(x, w0p3, hx, hxb, N);

    // pass 1 (full graph, near-exact -> tz -> mask)
    k_agg128<true><<<ga, 256, 0, stream>>>(hx, csr_off, csr_se, dinvF, b0, wk1, N);
    k_gemm_split<128, false><<<gbm, 256, 0, stream>>>(wk1, w1p3, wk2, nullptr, N);
    k_agg128<true><<<ga, 256, 0, stream>>>(wk2, csr_off, csr_se, dinvF, b1, wk1, N);
    k_gemm_split<64, false><<<gbm, 256, 0, stream>>>(wk1, w2p3, wk2, nullptr, N);
    k_agg64<<<ga, 256, 0, stream>>>(wk2, csr_off, csr_se, dinvF, b2, tz, N);

    // edge sampling in CSR order (writes survive + dinvM), wave-per-node
    k_surv<<<ga, 256, 0, stream>>>(tz, csr_off, csr_se, survive, dinvM, N);

    // pass 2 (post-mask: bf16 gathers + bf16 MFMA GEMMs, plane-0 weights)
    k_agg128b<true><<<ga, 256, 0, stream>>>(hxb, csr_off, csr_se, survive, dinvM, b0, wk1b, N);
    k_gemm_mfma<128><<<gbm, 256, 0, stream>>>(wk1b, w1p3, wk2b, N);
    k_agg128b<true><<<ga, 256, 0, stream>>>(wk2b, csr_off, csr_se, survive, dinvM, b1, wk1b, N);
    k_gemm_mfma<64><<<gbm, 256, 0, stream>>>(wk1b, w2p3, wk2b, N);
    k_agg64b<<<ga, 256, 0, stream>>>(wk2b, csr_off, csr_se, dinvF, b2, out, N);
}